// Round 8
// baseline (273.970 us; speedup 1.0000x reference)
//
#include <hip/hip_runtime.h>
#include <hip/hip_bf16.h>
#include <cstdint>
#include <cstddef>

// Problem constants
#define S_LEN 2048
#define DMODEL 2048
#define NHEADS 8
#define DHEAD 128
#define INNER_DIM 1024
#define BATCH 2

typedef __bf16 bf16;
typedef __bf16 bf16x8 __attribute__((ext_vector_type(8)));
typedef __bf16 bf16x4 __attribute__((ext_vector_type(4)));
typedef float f32x4 __attribute__((ext_vector_type(4)));

#define VMCNT(n) asm volatile("s_waitcnt vmcnt(" #n ")" ::: "memory")
#define BAR()                                \
  do {                                       \
    asm volatile("" ::: "memory");           \
    __builtin_amdgcn_s_barrier();            \
    asm volatile("" ::: "memory");           \
  } while (0)

__device__ __forceinline__ void gload_lds16(const void* g, void* l) {
  __builtin_amdgcn_global_load_lds(
      (const __attribute__((address_space(1))) void*)g,
      (__attribute__((address_space(3))) void*)l, 16, 0, 0);
}

__device__ __forceinline__ float sigmoidf_(float x) {
  return 1.0f / (1.0f + expf(-x));
}

// ---------------------------------------------------------------------------
// Fused prep kernel, range-dispatched on blockIdx.x (unchanged from round 6).
// ---------------------------------------------------------------------------
__global__ __launch_bounds__(256) void prep_kernel(
    const float* __restrict__ x, const float* __restrict__ wq,
    const float* __restrict__ wk, const float* __restrict__ wv,
    const float* __restrict__ wo, const float* __restrict__ Wb,
    const float* __restrict__ bbias, const float* __restrict__ alpha_log,
    bf16* __restrict__ wqkvb, bf16* __restrict__ wob, bf16* __restrict__ xb,
    float* __restrict__ beta, float* __restrict__ la_mean,
    float* __restrict__ la_d, float2* __restrict__ cs) {
  const int bid = blockIdx.x;
  const int tid = threadIdx.x;

  if (bid < 8192) {
    size_t i4 = ((size_t)bid * 256 + tid) * 4;
    const float* src;
    bf16* dst;
    size_t off;
    if (i4 < 2097152UL)       { src = wq; dst = wqkvb;           off = i4; }
    else if (i4 < 4194304UL)  { src = wk; dst = wqkvb + 2097152; off = i4 - 2097152UL; }
    else if (i4 < 6291456UL)  { src = wv; dst = wqkvb + 4194304; off = i4 - 4194304UL; }
    else                      { src = wo; dst = wob;             off = i4 - 6291456UL; }
    float4 v = *(const float4*)(src + off);
    bf16x4 o;
    o[0] = (bf16)v.x; o[1] = (bf16)v.y; o[2] = (bf16)v.z; o[3] = (bf16)v.w;
    *(bf16x4*)(dst + off) = o;
  } else if (bid < 9216) {
    const int n = (bid - 8192) * 4 + (tid >> 6);
    const int lane = tid & 63;
    float acc[8];
#pragma unroll
    for (int h = 0; h < 8; h++) acc[h] = 0.0f;
    const float4* x4 = (const float4*)(x + (size_t)n * DMODEL);
    bf16* xbr = xb + (size_t)n * DMODEL;
    for (int d4 = lane; d4 < DMODEL / 4; d4 += 64) {
      float4 xv = x4[d4];
      bf16x4 o;
      o[0] = (bf16)xv.x; o[1] = (bf16)xv.y; o[2] = (bf16)xv.z; o[3] = (bf16)xv.w;
      *(bf16x4*)(xbr + d4 * 4) = o;
#pragma unroll
      for (int h = 0; h < 8; h++) {
        float4 wv2 = ((const float4*)(Wb + (size_t)h * DMODEL))[d4];
        acc[h] += xv.x * wv2.x + xv.y * wv2.y + xv.z * wv2.z + xv.w * wv2.w;
      }
    }
#pragma unroll
    for (int off = 32; off; off >>= 1)
#pragma unroll
      for (int h = 0; h < 8; h++) acc[h] += __shfl_down(acc[h], off);
    if (lane == 0) {
#pragma unroll
      for (int h = 0; h < 8; h++)
        beta[(size_t)n * 8 + h] = sigmoidf_(acc[h] + bbias[h]);
    }
  } else if (bid < 9728) {
    int idx = (bid - 9216) * 256 + tid;  // < 131072 = 2048*64
    int s = idx >> 6, j = idx & 63;
    float f = (float)s * expf(-(float)j * (9.210340371976184f / 64.0f));
    float sn, c;
    sincosf(f, &sn, &c);
    cs[idx] = make_float2(c, sn);
  } else {
    if (tid >= 64) return;
    const int h = bid - 9728;
    const int lane = tid;
    float a1 = sigmoidf_(alpha_log[h * 128 + lane]);
    float a2 = sigmoidf_(alpha_log[h * 128 + 64 + lane]);
    la_d[h * 128 + lane] = logf(a1);
    la_d[h * 128 + 64 + lane] = logf(a2);
    float s = a1 + a2;
    for (int off = 32; off; off >>= 1) s += __shfl_down(s, off);
    if (lane == 0) la_mean[h] = logf(fmaxf(s * (1.0f / 128.0f), 1e-6f));
  }
}

// ---------------------------------------------------------------------------
// QKV projection: 128x384-tile, BK=32, 4-phase bf16 GEMM, full-fill 256
// blocks. ROUND-8: LDS halved to 2 x 32KB = 64KB -> 2 blocks/CU (was the
// only occupancy blocker at 128KB; VGPR 104 <= 128 allows 16 waves/CU).
// Cross-block overlap hides barrier/vmcnt stalls (m114 mechanism).
//
// Per K-tile (32-deep): stage ops A,B0,B1,B2 (8KB each = 128 rows x 64B;
// per wave 16 rows, lane: row=w*16+(lane>>2), granule=lane&3). Swizzle:
// granule XOR ((row>>1)&3) — balanced (every bank 8 dwords/wave-read,
// 2-way max = free). B rows permuted (qn,wn,nf)-major as before.
// Phases (6 MFMA each, walk 00->01->11->10, frags held):
//  p0: read A-q0(2)+B-q0(3); stage B0(t+1); VMCNT(2) [t=63: 0]
//  p1: read B-q1(3);         stage B1(t+1)
//  p2: read A-q1(2, ovwr);   stage B2(t+1)
//  p3: no reads;             stage A(t+2) into CURRENT buf;
//      VMCNT(2) [t=62: 1; t=63: none]
// Ledger invariant entering p0(t): outstanding = [B2(t), A(t+1)].
// Traced steady + prologue (A0,B0,B1,B2,A1; VMCNT(2)) + tails. Min load
// age at drain = 2 phases.
// ---------------------------------------------------------------------------
#define QKV_K 2048
#define QKV_NT 64  // K / 32

__global__ __launch_bounds__(512, 2) void qkv_gemm8p_kernel(
    const bf16* __restrict__ A, const bf16* __restrict__ Bm,
    bf16* __restrict__ C, bf16* __restrict__ vt) {
  __shared__ __align__(16) bf16 smem[2][16384];  // buf: A[0,4096) B[4096,16384) elems

  const int id = blockIdx.x;
  const int wg = (id & 7) * 32 + (id >> 3);
  const int tile_n = (wg >> 5) * 384;
  const int tile_m = (wg & 31) * 128;

  const int tid = threadIdx.x;
  const int lane = tid & 63;
  const int w = tid >> 6;
  const int wm = w >> 2;  // 0..1 -> rows wm*64
  const int wn = w & 3;   // 0..3 -> cols wn*96
  const int lr = lane & 15;
  const int kq = lane >> 4;

  // staging lane constants: op = 128 rows x 64B; wave w covers 16 rows
  const int srow = w * 16 + (lane >> 2);  // row within op (0..127)
  const int g = lane & 3;                 // granule within row

  // A: op rows == tile rows directly
  const size_t AoffL =
      (size_t)(tile_m + srow) * QKV_K + (size_t)((g ^ ((srow >> 1) & 3)) * 8);
  // B ops b=0..2: ldsr = b*128 + srow; permuted -> global col
  size_t Boff[3];
#pragma unroll
  for (int b = 0; b < 3; ++b) {
    const int ldsr = b * 128 + srow;
    const int qn = ldsr >= 192 ? 1 : 0;
    const int rem = ldsr - qn * 192;
    const int wng = rem / 48;
    const int rr = rem - wng * 48;
    const int gcol = wng * 96 + qn * 48 + rr;
    Boff[b] = (size_t)(tile_n + gcol) * QKV_K +
              (size_t)((g ^ ((ldsr >> 1) & 3)) * 8);
  }

  f32x4 acc[4][6];
#pragma unroll
  for (int i = 0; i < 4; i++)
#pragma unroll
    for (int j = 0; j < 6; j++) acc[i][j] = (f32x4){0.f, 0.f, 0.f, 0.f};

  auto stageA = [&](int buf, int k0) {
    gload_lds16(A + AoffL + k0, &smem[buf][w * 512]);
  };
  auto stageB = [&](int buf, int k0, int b) {
    gload_lds16(Bm + Boff[b] + k0, &smem[buf][4096 + b * 4096 + w * 512]);
  };

  // prologue: A(0),B0(0),B1(0),B2(0),A(1); keep [B2(0), A(1)]
  stageA(0, 0);
  stageB(0, 0, 0);
  stageB(0, 0, 1);
  stageB(0, 0, 2);
  stageA(1, 32);
  VMCNT(2);
  BAR();

  for (int t = 0; t < QKV_NT; ++t) {
    const int buf = t & 1;
    const int k0n = (t + 1) * 32;
    const bool h1 = (t + 1 < QKV_NT);
    const bool h2 = (t + 2 < QKV_NT);
    const bf16* ldsA = smem[buf];
    const bf16* ldsB = smem[buf] + 4096;

    bf16x8 af[2], b0f[3], b1f[3];

    // ---- p0: read A-q0 + B-q0; stage B0(t+1); MFMA (0,0..2) ----
#pragma unroll
    for (int mi = 0; mi < 2; ++mi) {
      const int row = wm * 64 + mi * 16 + lr;
      af[mi] = *(const bf16x8*)&ldsA[row * 32 + ((kq ^ ((row >> 1) & 3)) * 8)];
    }
#pragma unroll
    for (int ni = 0; ni < 3; ++ni) {
      const int row = wn * 48 + ni * 16 + lr;
      b0f[ni] = *(const bf16x8*)&ldsB[row * 32 + ((kq ^ ((row >> 1) & 3)) * 8)];
    }
    if (h1) stageB(buf ^ 1, k0n, 0);
    __builtin_amdgcn_s_setprio(1);
#pragma unroll
    for (int mi = 0; mi < 2; ++mi)
#pragma unroll
      for (int ni = 0; ni < 3; ++ni)
        acc[mi][ni] = __builtin_amdgcn_mfma_f32_16x16x32_bf16(
            af[mi], b0f[ni], acc[mi][ni], 0, 0, 0);
    __builtin_amdgcn_s_setprio(0);
    if (h1) VMCNT(2);
    else VMCNT(0);
    BAR();

    // ---- p1: read B-q1; stage B1(t+1); MFMA (0,3..5) ----
#pragma unroll
    for (int ni = 0; ni < 3; ++ni) {
      const int row = 192 + wn * 48 + ni * 16 + lr;
      b1f[ni] = *(const bf16x8*)&ldsB[row * 32 + ((kq ^ ((row >> 1) & 3)) * 8)];
    }
    if (h1) stageB(buf ^ 1, k0n, 1);
    __builtin_amdgcn_s_setprio(1);
#pragma unroll
    for (int mi = 0; mi < 2; ++mi)
#pragma unroll
      for (int ni = 0; ni < 3; ++ni)
        acc[mi][3 + ni] = __builtin_amdgcn_mfma_f32_16x16x32_bf16(
            af[mi], b1f[ni], acc[mi][3 + ni], 0, 0, 0);
    __builtin_amdgcn_s_setprio(0);
    BAR();

    // ---- p2: read A-q1 (overwrite); stage B2(t+1); MFMA (1,3..5) ----
#pragma unroll
    for (int mi = 0; mi < 2; ++mi) {
      const int row = wm * 64 + 32 + mi * 16 + lr;
      af[mi] = *(const bf16x8*)&ldsA[row * 32 + ((kq ^ ((row >> 1) & 3)) * 8)];
    }
    if (h1) stageB(buf ^ 1, k0n, 2);
    __builtin_amdgcn_s_setprio(1);
#pragma unroll
    for (int mi = 0; mi < 2; ++mi)
#pragma unroll
      for (int ni = 0; ni < 3; ++ni)
        acc[2 + mi][3 + ni] = __builtin_amdgcn_mfma_f32_16x16x32_bf16(
            af[mi], b1f[ni], acc[2 + mi][3 + ni], 0, 0, 0);
    __builtin_amdgcn_s_setprio(0);
    BAR();

    // ---- p3: no reads (B-q0 live); stage A(t+2) into CURRENT buf; MFMA (1,0..2)
    if (h2) stageA(buf, (t + 2) * 32);
    __builtin_amdgcn_s_setprio(1);
#pragma unroll
    for (int mi = 0; mi < 2; ++mi)
#pragma unroll
      for (int ni = 0; ni < 3; ++ni)
        acc[2 + mi][ni] = __builtin_amdgcn_mfma_f32_16x16x32_bf16(
            af[mi], b0f[ni], acc[2 + mi][ni], 0, 0, 0);
    __builtin_amdgcn_s_setprio(0);
    if (h1) {
      if (h2) VMCNT(2);
      else VMCNT(1);
    }
    BAR();
  }

  // epilogue: acc -> q/kk/vv (+ vt for z==2)  (unchanged mapping)
  const int rb = kq * 4;
#pragma unroll
  for (int mi = 0; mi < 4; ++mi) {
    const int row0 = tile_m + wm * 64 + mi * 16 + rb;
#pragma unroll
    for (int ni = 0; ni < 6; ++ni) {
      const int col = tile_n + wn * 96 + ni * 16 + lr;
      const int z = col >> 10;
      const int cz = col & 1023;
      bf16* Cz = C + (size_t)z * 4194304UL;
#pragma unroll
      for (int r2 = 0; r2 < 4; ++r2)
        Cz[(size_t)(row0 + r2) * 1024 + cz] = (bf16)acc[mi][ni][r2];
      if (z == 2) {
        const int bb2 = row0 >> 11;
        const int ss = row0 & 2047;
        bf16x4 o4;
#pragma unroll
        for (int r2 = 0; r2 < 4; ++r2) o4[r2] = (bf16)acc[mi][ni][r2];
        *(bf16x4*)&vt[(((size_t)bb2 * 8 + (cz >> 7)) * 128 + (cz & 127)) * 2048 +
                      ss] = o4;
      }
    }
  }
}

// ---------------------------------------------------------------------------
// Output projection: 128x256-tile 4-phase bf16 GEMM -> fp32 C (round 6).
// ---------------------------------------------------------------------------
#define OP_K 1024
#define OP_NT 16  // K / 64

__global__ __launch_bounds__(512, 2) void oproj_kernel(
    const bf16* __restrict__ A, const bf16* __restrict__ Bm,
    float* __restrict__ C) {
  __shared__ __align__(16) bf16 smem[2][24576];  // A[0,8192) B[8192,24576)

  const int id = blockIdx.x;
  const int wg = (id & 7) * 32 + (id >> 3);
  const int tile_n = (wg >> 5) * 256;
  const int tile_m = (wg & 31) * 128;

  const int tid = threadIdx.x;
  const int lane = tid & 63;
  const int w = tid >> 6;
  const int wm = w >> 2;  // 0..1
  const int wn = w & 3;   // 0..3
  const int lr = lane & 15;
  const int kq = lane >> 4;

  const int srow = lane >> 3;
  const int slot = lane & 7;
  const int sgo = (slot ^ srow) * 8;
  const int rloc = w * 8 + srow;

  size_t Aoff[2], Boff[4];
#pragma unroll
  for (int a = 0; a < 2; ++a)
    Aoff[a] = (size_t)(tile_m + a * 64 + rloc) * OP_K + sgo;
#pragma unroll
  for (int b = 0; b < 4; ++b) {
    const int ldsr = b * 64 + rloc;
    const int qn = ldsr >= 128 ? 1 : 0;
    const int rem = ldsr - qn * 128;
    const int wng = rem >> 5;
    const int rr = rem & 31;
    const int gcol = wng * 64 + qn * 32 + rr;
    Boff[b] = (size_t)(tile_n + gcol) * OP_K + sgo;
  }

  f32x4 acc[4][4];
#pragma unroll
  for (int i = 0; i < 4; i++)
#pragma unroll
    for (int j = 0; j < 4; j++) acc[i][j] = (f32x4){0.f, 0.f, 0.f, 0.f};

  auto stageAA = [&](int buf, int k0) {
#pragma unroll
    for (int a = 0; a < 2; ++a)
      gload_lds16(A + Aoff[a] + k0, &smem[buf][(a * 64 + w * 8) * 64]);
  };
  auto stageB2 = [&](int buf, int k0, int b0) {
#pragma unroll
    for (int u = 0; u < 2; ++u)
      gload_lds16(Bm + Boff[b0 + u] + k0,
                  &smem[buf][8192 + ((b0 + u) * 64 + w * 8) * 64]);
  };

  // prologue
  stageAA(0, 0);
  stageB2(0, 0, 0);
  stageAA(1, 64);
  stageB2(0, 0, 2);
  VMCNT(4);
  BAR();

  for (int t = 0; t < OP_NT; ++t) {
    const int buf = t & 1;
    const int k0n = (t + 1) * 64;
    const bool h1 = (t + 1 < OP_NT);
    const bool h2 = (t + 2 < OP_NT);
    const bf16* ldsA = smem[buf];
    const bf16* ldsB = smem[buf] + 8192;

    bf16x8 af[2][2], b0f[2][2], b1f[2][2];

    // ---- p0 ----
#pragma unroll
    for (int mi = 0; mi < 2; ++mi)
#pragma unroll
      for (int ks = 0; ks < 2; ++ks)
        af[mi][ks] = *(const bf16x8*)&ldsA[(wm * 64 + mi * 16 + lr) * 64 +
                                           (((ks * 4 + kq) ^ (lr & 7)) * 8)];
#pragma unroll
    for (int ni = 0; ni < 2; ++ni)
#pragma unroll
      for (int ks = 0; ks < 2; ++ks)
        b0f[ni][ks] = *(const bf16x8*)&ldsB[(wn * 32 + ni * 16 + lr) * 64 +
                                            (((ks * 4 + kq) ^ (lr & 7)) * 8)];
    if (h1) stageB2(buf ^ 1, k0n, 0);
    __builtin_amdgcn_s_setprio(1);
#pragma unroll
    for (int mi = 0; mi < 2; ++mi)
#pragma unroll
      for (int ni = 0; ni < 2; ++ni)
#pragma unroll
        for (int ks = 0; ks < 2; ++ks)
          acc[mi][ni] = __builtin_amdgcn_mfma_f32_16x16x32_bf16(
              af[mi][ks], b0f[ni][ks], acc[mi][ni], 0, 0, 0);
    __builtin_amdgcn_s_setprio(0);
    if (h1) VMCNT(4);
    else VMCNT(0);
    BAR();

    // ---- p1 ----
#pragma unroll
    for (int ni = 0; ni < 2; ++ni)
#pragma unroll
      for (int ks = 0; ks < 2; ++ks)
        b1f[ni][ks] = *(const bf16x8*)&ldsB[(128 + wn * 32 + ni * 16 + lr) * 64 +
                                            (((ks * 4 + kq) ^ (lr & 7)) * 8)];
    if (h1) stageB2(buf ^ 1, k0n, 2);
    __builtin_amdgcn_s_setprio(1);
#pragma unroll
    for (int mi = 0; mi < 2; ++mi)
#pragma unroll
      for (int ni = 0; ni < 2; ++ni)
#pragma unroll
        for (int ks = 0; ks < 2; ++ks)
          acc[mi][2 + ni] = __builtin_amdgcn_mfma_f32_16x16x32_bf16(
              af[mi][ks], b1f[ni][ks], acc[mi][2 + ni], 0, 0, 0);
    __builtin_amdgcn_s_setprio(0);
    BAR();

    // ---- p2 ----
#pragma unroll
    for (int mi = 0; mi < 2; ++mi)
#pragma unroll
      for (int ks = 0; ks < 2; ++ks)
        af[mi][ks] = *(const bf16x8*)&ldsA[(wm * 64 + 32 + mi * 16 + lr) * 64 +
                                           (((ks * 4 + kq) ^ (lr & 7)) * 8)];
    __builtin_amdgcn_s_setprio(1);
#pragma unroll
    for (int mi = 0; mi < 2; ++mi)
#pragma unroll
      for (int ni = 0; ni < 2; ++ni)
#pragma unroll
        for (int ks = 0; ks < 2; ++ks)
          acc[2 + mi][2 + ni] = __builtin_amdgcn_mfma_f32_16x16x32_bf16(
              af[mi][ks], b1f[ni][ks], acc[2 + mi][2 + ni], 0, 0, 0);
    __builtin_amdgcn_s_setprio(0);
    BAR();

    // ---- p3 ----
    if (h2) stageAA(buf, (t + 2) * 64);
    __builtin_amdgcn_s_setprio(1);
#pragma unroll
    for (int mi = 0; mi < 2; ++mi)
#pragma unroll
      for (int ni = 0; ni < 2; ++ni)
#pragma unroll
        for (int ks = 0; ks < 2; ++ks)
          acc[2 + mi][ni] = __builtin_amdgcn_mfma_f32_16x16x32_bf16(
              af[mi][ks], b0f[ni][ks], acc[2 + mi][ni], 0, 0, 0);
    __builtin_amdgcn_s_setprio(0);
    if (h1) {
      if (h2) VMCNT(4);
      else VMCNT(2);
    }
    BAR();
  }

  // epilogue: fp32 C
  const int rb = kq * 4;
#pragma unroll
  for (int i = 0; i < 4; ++i) {
    const int row0 = tile_m + wm * 64 + (i >> 1) * 32 + (i & 1) * 16 + rb;
#pragma unroll
    for (int j = 0; j < 4; ++j) {
      const int col = tile_n + wn * 64 + (j >> 1) * 32 + (j & 1) * 16 + lr;
#pragma unroll
      for (int r2 = 0; r2 < 4; ++r2)
        C[(size_t)(row0 + r2) * 2048 + col] = acc[i][j][r2];
    }
  }
}

// ---------------------------------------------------------------------------
// RoPE in place on bf16 q and k, cos/sin from precomputed table (round 6).
// ---------------------------------------------------------------------------
__global__ __launch_bounds__(256) void rope_kernel(bf16* __restrict__ q,
                                                   bf16* __restrict__ k,
                                                   const float2* __restrict__ cs) {
  int idx = blockIdx.x * 256 + threadIdx.x;  // < 524288
  int j0 = (idx & 15) * 4;
  int nh = idx >> 4;  // n*8 + h, n < 4096
  int s = (nh >> 3) & (S_LEN - 1);
  size_t base = (size_t)nh * 128 + j0;
  bf16x4 qa = *(bf16x4*)&q[base], qb = *(bf16x4*)&q[base + 64];
  bf16x4 ka = *(bf16x4*)&k[base], kb = *(bf16x4*)&k[base + 64];
  const float2* c4 = cs + s * 64 + j0;
#pragma unroll
  for (int jj = 0; jj < 4; jj++) {
    float c = c4[jj].x;
    float sn = c4[jj].y;
    float q1 = (float)qa[jj], q2 = (float)qb[jj];
    qa[jj] = (bf16)(q1 * c - q2 * sn);
    qb[jj] = (bf16)(q2 * c + q1 * sn);
    float k1 = (float)ka[jj], k2 = (float)kb[jj];
    ka[jj] = (bf16)(k1 * c - k2 * sn);
    kb[jj] = (bf16)(k2 * c + k1 * sn);
  }
  *(bf16x4*)&q[base] = qa;
  *(bf16x4*)&q[base + 64] = qb;
  *(bf16x4*)&k[base] = ka;
  *(bf16x4*)&k[base + 64] = kb;
}

// ---------------------------------------------------------------------------
// MFMA banded-decay attention (round 6, no fused rope).
// ---------------------------------------------------------------------------
__global__ __launch_bounds__(256) void attn_mfma_kernel(
    const bf16* __restrict__ q, const bf16* __restrict__ k,
    const bf16* __restrict__ vt, const float* __restrict__ beta,
    const float* __restrict__ la_mean, bf16* __restrict__ outb) {
  const int s0 = blockIdx.x * 64;
  const int h = blockIdx.y;
  const int b = blockIdx.z;
  const int tid = threadIdx.x;
  const int w = tid >> 6;
  const int lane = tid & 63;
  const int lr = lane & 15;
  const int kq = lane >> 4;  // quad
  const float la = la_mean[h];

  __shared__ __align__(16) bf16 Ps[4][2][16][72];

  const int sg = s0 + w * 16;
  const size_t qbase =
      ((size_t)b * S_LEN + (sg + lr)) * INNER_DIM + h * 128 + kq * 8;
  bf16x8 aq[4];
#pragma unroll
  for (int ks = 0; ks < 4; ks++)
    aq[ks] = *(const bf16x8*)&q[qbase + ks * 32];

  f32x4 O[8];
#pragma unroll
  for (int en = 0; en < 8; en++) O[en] = (f32x4){0.f, 0.f, 0.f, 0.f};

  const size_t kbase = (size_t)b * S_LEN * INNER_DIM + h * 128 + kq * 8;
  const size_t vtbase = ((size_t)b * 8 + h) * 128 * 2048;

#pragma unroll
  for (int tile = 0; tile < 2; tile++) {
    const int tb = s0 - 64 + tile * 64;
    f32x4 sc[4];
#pragma unroll
    for (int nt = 0; nt < 4; nt++) sc[nt] = (f32x4){0.f, 0.f, 0.f, 0.f};
#pragma unroll
    for (int nt = 0; nt < 4; nt++) {
      int t = tb + nt * 16 + lr;
      int tc = t > 0 ? t : 0;
#pragma unroll
      for (int ks = 0; ks < 4; ks++) {
        bf16x8 bk = *(const bf16x8*)&k[kbase + (size_t)tc * INNER_DIM + ks * 32];
        sc[nt] = __builtin_amdgcn_mfma_f32_16x16x32_bf16(aq[ks], bk, sc[nt],
                                                         0, 0, 0);
      }
    }
#pragma unroll
    for (int nt = 0; nt < 4; nt++) {
      int t = tb + nt * 16 + lr;
      int tc = t > 0 ? t : 0;
      float bt = beta[((size_t)b * S_LEN + tc) * 8 + h];
#pragma unroll
      for (int reg = 0; reg < 4; reg++) {
        int qrow = sg + kq * 4 + reg;
        int td = qrow - t;
        float wgt = 0.0f;
        if (t >= 0 && td >= 0 && td < 64)
          wgt = sc[nt][reg] * __expf((float)td * la) * bt;
        Ps[w][tile][kq * 4 + reg][nt * 16 + lr] = (bf16)wgt;
      }
    }
    __syncthreads();
    bf16x8 ap[2];
#pragma unroll
    for (int ks2 = 0; ks2 < 2; ks2++)
      ap[ks2] = *(const bf16x8*)&Ps[w][tile][lr][ks2 * 32 + kq * 8];
#pragma unroll
    for (int en = 0; en < 8; en++) {
#pragma unroll
      for (int ks2 = 0; ks2 < 2; ks2++) {
        int t0f = tb + ks2 * 32 + kq * 8;
        int tcf = t0f > 0 ? t0f : 0;
        bf16x8 bv = *(const bf16x8*)&vt[vtbase + (size_t)(en * 16 + lr) * 2048 +
                                        tcf];
        O[en] = __builtin_amdgcn_mfma_f32_16x16x32_bf16(ap[ks2], bv, O[en], 0,
                                                        0, 0);
      }
    }
  }
  const size_t obase = (size_t)b * S_LEN * INNER_DIM + h * 128;
#pragma unroll
  for (int en = 0; en < 8; en++) {
#pragma unroll
    for (int reg = 0; reg < 4; reg++) {
      int qrow = sg + kq * 4 + reg;
      outb[obase + (size_t)qrow * INNER_DIM + en * 16 + lr] =
          (bf16)O[en][reg];
    }
  }
}

// ---------------------------------------------------------------------------
// Stage 1: partial state per 32-step chunk (round 6).
// ---------------------------------------------------------------------------
__global__ __launch_bounds__(256) void state_partial_kernel(
    const bf16* __restrict__ k, const bf16* __restrict__ v,
    const float* __restrict__ beta, const float* __restrict__ la_d,
    float* __restrict__ part) {
  const int bh = blockIdx.x;
  const int chunk = blockIdx.y;
  const int b = bh >> 3, h = bh & 7;
  const int t0 = S_LEN - 512 + chunk * 32;
  const int tid = threadIdx.x;
  const int d = tid >> 1;
  const int eh = (tid & 1) * 64;

  __shared__ float ks[32][128];
  __shared__ float vsm[32][128];
  __shared__ float bs[32];

  const size_t bh_off = ((size_t)b * S_LEN) * INNER_DIM + (size_t)h * 128;
  for (int u = tid; u < 32 * 16; u += 256) {
    int r = u >> 4, c8 = (u & 15) * 8;
    bf16x8 kv = *(const bf16x8*)&k[bh_off + (size_t)(t0 + r) * INNER_DIM + c8];
    bf16x8 vv = *(const bf16x8*)&v[bh_off + (size_t)(t0 + r) * INNER_DIM + c8];
#pragma unroll
    for (int j = 0; j < 8; j++) {
      ks[r][c8 + j] = (float)kv[j];
      vsm[r][c8 + j] = (float)vv[j];
    }
  }
  if (tid < 32) bs[tid] = beta[((size_t)b * S_LEN + t0 + tid) * 8 + h];
  __syncthreads();

  const float lad = la_d[h * 128 + d];
  float acc[64];
#pragma unroll
  for (int e = 0; e < 64; e++) acc[e] = 0.0f;

  for (int tl = 0; tl < 32; tl++) {
    int m = (S_LEN - 1) - (t0 + tl);
    float f = __expf((float)m * lad);
    float coef = bs[tl] * ks[tl][d] * f;
    if (coef != 0.0f) {
#pragma unroll
      for (int e = 0; e < 64; e += 4) {
        float4 vv = *(const float4*)&vsm[tl][eh + e];
        acc[e + 0] = fmaf(coef, vv.x, acc[e + 0]);
        acc[e + 1] = fmaf(coef, vv.y, acc[e + 1]);
        acc[e + 2] = fmaf(coef, vv.z, acc[e + 2]);
        acc[e + 3] = fmaf(coef, vv.w, acc[e + 3]);
      }
    }
  }
  float* pp = part + (((size_t)chunk * 16 + bh) * 16384 + (size_t)d * 128 + eh);
#pragma unroll
  for (int e = 0; e < 64; e += 4) {
    float4 o = {acc[e + 0], acc[e + 1], acc[e + 2], acc[e + 3]};
    *(float4*)&pp[e] = o;
  }
}

// ---------------------------------------------------------------------------
// Stage 2: sum the 16 chunk partials into the final state (round 6).
// ---------------------------------------------------------------------------
__global__ __launch_bounds__(256) void state_reduce_kernel(
    const float* __restrict__ part, float* __restrict__ state) {
  size_t off = ((size_t)blockIdx.x * 256 + threadIdx.x) * 4;
  float4 s = {0.f, 0.f, 0.f, 0.f};
#pragma unroll
  for (int c = 0; c < 16; c++) {
    float4 p = *(const float4*)&part[(size_t)c * 262144 + off];
    s.x += p.x; s.y += p.y; s.z += p.z; s.w += p.w;
  }
  *(float4*)&state[off] = s;
}

// ---------------------------------------------------------------------------
extern "C" void kernel_launch(void* const* d_in, const int* in_sizes, int n_in,
                              void* d_out, int out_size, void* d_ws,
                              size_t ws_size, hipStream_t stream) {
  const float* x = (const float*)d_in[0];
  const float* Wq = (const float*)d_in[1];
  const float* Wk = (const float*)d_in[2];
  const float* Wv = (const float*)d_in[3];
  const float* Wo = (const float*)d_in[4];
  const float* Wb = (const float*)d_in[5];
  const float* bb = (const float*)d_in[6];
  const float* alog = (const float*)d_in[7];
  float* out = (float*)d_out;

  char* ws = (char*)d_ws;
  bf16* xb = (bf16*)(ws);                      // 16 MB
  float* part = (float*)(ws);                  // reuses xb after QKV GEMM
  bf16* wqkvb = (bf16*)(ws + 16777216UL);      // 12 MB
  bf16* wob = (bf16*)(ws + 29360128UL);        // 4 MB
  bf16* q = (bf16*)(ws + 33554432UL);          // 8 MB
  bf16* kk = (bf16*)(ws + 41943040UL);         // 8 MB
  bf16* vv = (bf16*)(ws + 50331648UL);         // 8 MB
  bf16* attnb = (bf16*)(ws + 58720256UL);      // 8 MB
  bf16* vt = (bf16*)(ws + 67108864UL);         // 8 MB (V transposed)
  float* beta = (float*)(ws + 75497472UL);     // 128 KB
  float* la_mean = (float*)(ws + 75628544UL);  // 32 B
  float* la_d = (float*)(ws + 75628800UL);     // 4 KB
  float2* cs = (float2*)(ws + 75632896UL);     // 1 MB rope table

  prep_kernel<<<9736, 256, 0, stream>>>(x, Wq, Wk, Wv, Wo, Wb, bb, alog,
                                        wqkvb, wob, xb, beta, la_mean, la_d,
                                        cs);
  qkv_gemm8p_kernel<<<256, 512, 0, stream>>>(xb, wqkvb, q, vt);
  rope_kernel<<<2048, 256, 0, stream>>>(q, kk, cs);
  attn_mfma_kernel<<<dim3(S_LEN / 64, NHEADS, BATCH), 256, 0, stream>>>(
      q, kk, vt, beta, la_mean, attnb);
  state_partial_kernel<<<dim3(16, 16), 256, 0, stream>>>(kk, vv, beta, la_d,
                                                         part);
  state_reduce_kernel<<<256, 256, 0, stream>>>(part, out + 8388608);
  oproj_kernel<<<256, 512, 0, stream>>>(attnb, wob, out);
}

// Round 9
// 261.123 us; speedup vs baseline: 1.0492x; 1.0492x over previous
//
#include <hip/hip_runtime.h>
#include <hip/hip_bf16.h>
#include <cstdint>
#include <cstddef>

// Problem constants
#define S_LEN 2048
#define DMODEL 2048
#define NHEADS 8
#define DHEAD 128
#define INNER_DIM 1024
#define BATCH 2

typedef __bf16 bf16;
typedef __bf16 bf16x8 __attribute__((ext_vector_type(8)));
typedef __bf16 bf16x4 __attribute__((ext_vector_type(4)));
typedef float f32x4 __attribute__((ext_vector_type(4)));

#define VMCNT(n) asm volatile("s_waitcnt vmcnt(" #n ")" ::: "memory")
#define BAR()                                \
  do {                                       \
    asm volatile("" ::: "memory");           \
    __builtin_amdgcn_s_barrier();            \
    asm volatile("" ::: "memory");           \
  } while (0)

__device__ __forceinline__ void gload_lds16(const void* g, void* l) {
  __builtin_amdgcn_global_load_lds(
      (const __attribute__((address_space(1))) void*)g,
      (__attribute__((address_space(3))) void*)l, 16, 0, 0);
}

__device__ __forceinline__ float sigmoidf_(float x) {
  return 1.0f / (1.0f + expf(-x));
}

// ---------------------------------------------------------------------------
// Fused prep kernel, range-dispatched on blockIdx.x (unchanged from round 6).
// ---------------------------------------------------------------------------
__global__ __launch_bounds__(256) void prep_kernel(
    const float* __restrict__ x, const float* __restrict__ wq,
    const float* __restrict__ wk, const float* __restrict__ wv,
    const float* __restrict__ wo, const float* __restrict__ Wb,
    const float* __restrict__ bbias, const float* __restrict__ alpha_log,
    bf16* __restrict__ wqkvb, bf16* __restrict__ wob, bf16* __restrict__ xb,
    float* __restrict__ beta, float* __restrict__ la_mean,
    float* __restrict__ la_d, float2* __restrict__ cs) {
  const int bid = blockIdx.x;
  const int tid = threadIdx.x;

  if (bid < 8192) {
    size_t i4 = ((size_t)bid * 256 + tid) * 4;
    const float* src;
    bf16* dst;
    size_t off;
    if (i4 < 2097152UL)       { src = wq; dst = wqkvb;           off = i4; }
    else if (i4 < 4194304UL)  { src = wk; dst = wqkvb + 2097152; off = i4 - 2097152UL; }
    else if (i4 < 6291456UL)  { src = wv; dst = wqkvb + 4194304; off = i4 - 4194304UL; }
    else                      { src = wo; dst = wob;             off = i4 - 6291456UL; }
    float4 v = *(const float4*)(src + off);
    bf16x4 o;
    o[0] = (bf16)v.x; o[1] = (bf16)v.y; o[2] = (bf16)v.z; o[3] = (bf16)v.w;
    *(bf16x4*)(dst + off) = o;
  } else if (bid < 9216) {
    const int n = (bid - 8192) * 4 + (tid >> 6);
    const int lane = tid & 63;
    float acc[8];
#pragma unroll
    for (int h = 0; h < 8; h++) acc[h] = 0.0f;
    const float4* x4 = (const float4*)(x + (size_t)n * DMODEL);
    bf16* xbr = xb + (size_t)n * DMODEL;
    for (int d4 = lane; d4 < DMODEL / 4; d4 += 64) {
      float4 xv = x4[d4];
      bf16x4 o;
      o[0] = (bf16)xv.x; o[1] = (bf16)xv.y; o[2] = (bf16)xv.z; o[3] = (bf16)xv.w;
      *(bf16x4*)(xbr + d4 * 4) = o;
#pragma unroll
      for (int h = 0; h < 8; h++) {
        float4 wv2 = ((const float4*)(Wb + (size_t)h * DMODEL))[d4];
        acc[h] += xv.x * wv2.x + xv.y * wv2.y + xv.z * wv2.z + xv.w * wv2.w;
      }
    }
#pragma unroll
    for (int off = 32; off; off >>= 1)
#pragma unroll
      for (int h = 0; h < 8; h++) acc[h] += __shfl_down(acc[h], off);
    if (lane == 0) {
#pragma unroll
      for (int h = 0; h < 8; h++)
        beta[(size_t)n * 8 + h] = sigmoidf_(acc[h] + bbias[h]);
    }
  } else if (bid < 9728) {
    int idx = (bid - 9216) * 256 + tid;  // < 131072 = 2048*64
    int s = idx >> 6, j = idx & 63;
    float f = (float)s * expf(-(float)j * (9.210340371976184f / 64.0f));
    float sn, c;
    sincosf(f, &sn, &c);
    cs[idx] = make_float2(c, sn);
  } else {
    if (tid >= 64) return;
    const int h = bid - 9728;
    const int lane = tid;
    float a1 = sigmoidf_(alpha_log[h * 128 + lane]);
    float a2 = sigmoidf_(alpha_log[h * 128 + 64 + lane]);
    la_d[h * 128 + lane] = logf(a1);
    la_d[h * 128 + 64 + lane] = logf(a2);
    float s = a1 + a2;
    for (int off = 32; off; off >>= 1) s += __shfl_down(s, off);
    if (lane == 0) la_mean[h] = logf(fmaxf(s * (1.0f / 128.0f), 1e-6f));
  }
}

// ---------------------------------------------------------------------------
// QKV projection: 128x384-tile, BK=64, 4-phase bf16 GEMM, full-fill 256
// blocks (round-6 verified core, 62 us). ROUND-9 ADDITION: RoPE fused into
// the epilogue. After the K-loop the 128KB LDS is dead; blocks with q/k
// columns (tile_n < 2048) stage their z<2 acc columns into LDS (stride 392,
// row-direction access conflict-free), barrier once, and each thread reads
// its rotation partner (col +-64; always in the same 128-col group, hence
// the same block) to compute the ROPED output in one pass:
//   d = col&127; dj = d&63; (c,s) = cs[(row&2047)*64 + dj]
//   d<64:  out = own*c - partner*s      (matches old rope lo path)
//   d>=64: out = own*c + partner*s      (matches old rope hi path)
// v (z==2) and vt writes unchanged (register-direct). rope_kernel deleted.
// ---------------------------------------------------------------------------
#define QKV_K 2048
#define QKV_NT 32  // K / 64
#define LSTR 392   // epilogue LDS stride (elems); 128*392*2 = 100352 <= 131072

__global__ __launch_bounds__(512, 2) void qkv_gemm8p_kernel(
    const bf16* __restrict__ A, const bf16* __restrict__ Bm,
    bf16* __restrict__ C, bf16* __restrict__ vt,
    const float2* __restrict__ cs) {
  __shared__ __align__(16) bf16 smem[2][32768];  // buf: A[0,8192) B[8192,32768)

  const int id = blockIdx.x;
  const int wg = (id & 7) * 32 + (id >> 3);
  const int tile_n = (wg >> 5) * 384;
  const int tile_m = (wg & 31) * 128;

  const int tid = threadIdx.x;
  const int lane = tid & 63;
  const int w = tid >> 6;
  const int wm = w >> 2;  // 0..1 -> rows wm*64
  const int wn = w & 3;   // 0..3 -> cols wn*96
  const int lr = lane & 15;
  const int kq = lane >> 4;

  const int srow = lane >> 3;
  const int slot = lane & 7;
  const int sgo = (slot ^ srow) * 8;
  const int rloc = w * 8 + srow;

  size_t Aoff[2], Boff[6];
#pragma unroll
  for (int a = 0; a < 2; ++a)
    Aoff[a] = (size_t)(tile_m + a * 64 + rloc) * QKV_K + sgo;
#pragma unroll
  for (int b = 0; b < 6; ++b) {
    const int ldsr = b * 64 + rloc;
    const int qn = ldsr >= 192 ? 1 : 0;
    const int rem = ldsr - qn * 192;
    const int wng = rem / 48;
    const int rr = rem - wng * 48;
    const int gcol = wng * 96 + qn * 48 + rr;
    Boff[b] = (size_t)(tile_n + gcol) * QKV_K + sgo;
  }

  f32x4 acc[4][6];
#pragma unroll
  for (int i = 0; i < 4; i++)
#pragma unroll
    for (int j = 0; j < 6; j++) acc[i][j] = (f32x4){0.f, 0.f, 0.f, 0.f};

  auto stageAA = [&](int buf, int k0) {
#pragma unroll
    for (int a = 0; a < 2; ++a)
      gload_lds16(A + Aoff[a] + k0, &smem[buf][(a * 64 + w * 8) * 64]);
  };
  auto stageB2 = [&](int buf, int k0, int b0) {
#pragma unroll
    for (int u = 0; u < 2; ++u)
      gload_lds16(Bm + Boff[b0 + u] + k0,
                  &smem[buf][8192 + ((b0 + u) * 64 + w * 8) * 64]);
  };

  // prologue (order matters for the ledger)
  stageAA(0, 0);
  stageB2(0, 0, 0);
  stageB2(0, 0, 2);
  stageAA(1, 64);
  stageB2(0, 0, 4);
  VMCNT(4);
  BAR();

  for (int t = 0; t < QKV_NT; ++t) {
    const int buf = t & 1;
    const int k0n = (t + 1) * 64;
    const bool h1 = (t + 1 < QKV_NT);
    const bool h2 = (t + 2 < QKV_NT);
    const bf16* ldsA = smem[buf];
    const bf16* ldsB = smem[buf] + 8192;

    bf16x8 af[2][2], b0f[3][2], b1f[3][2];

    // ---- p0: read A-q0 + B-q0; stage b01(t+1); MFMA (0,0..2) ----
#pragma unroll
    for (int mi = 0; mi < 2; ++mi)
#pragma unroll
      for (int ks = 0; ks < 2; ++ks)
        af[mi][ks] = *(const bf16x8*)&ldsA[(wm * 64 + mi * 16 + lr) * 64 +
                                           (((ks * 4 + kq) ^ (lr & 7)) * 8)];
#pragma unroll
    for (int ni = 0; ni < 3; ++ni)
#pragma unroll
      for (int ks = 0; ks < 2; ++ks)
        b0f[ni][ks] = *(const bf16x8*)&ldsB[(wn * 48 + ni * 16 + lr) * 64 +
                                            (((ks * 4 + kq) ^ (lr & 7)) * 8)];
    if (h1) stageB2(buf ^ 1, k0n, 0);
    __builtin_amdgcn_s_setprio(1);
#pragma unroll
    for (int mi = 0; mi < 2; ++mi)
#pragma unroll
      for (int ni = 0; ni < 3; ++ni)
#pragma unroll
        for (int ks = 0; ks < 2; ++ks)
          acc[mi][ni] = __builtin_amdgcn_mfma_f32_16x16x32_bf16(
              af[mi][ks], b0f[ni][ks], acc[mi][ni], 0, 0, 0);
    __builtin_amdgcn_s_setprio(0);
    if (h1) VMCNT(4);
    else VMCNT(0);
    BAR();

    // ---- p1: read B-q1; stage b23(t+1); MFMA (0,3..5) ----
#pragma unroll
    for (int ni = 0; ni < 3; ++ni)
#pragma unroll
      for (int ks = 0; ks < 2; ++ks)
        b1f[ni][ks] = *(const bf16x8*)&ldsB[(192 + wn * 48 + ni * 16 + lr) * 64 +
                                            (((ks * 4 + kq) ^ (lr & 7)) * 8)];
    if (h1) stageB2(buf ^ 1, k0n, 2);
    __builtin_amdgcn_s_setprio(1);
#pragma unroll
    for (int mi = 0; mi < 2; ++mi)
#pragma unroll
      for (int ni = 0; ni < 3; ++ni)
#pragma unroll
        for (int ks = 0; ks < 2; ++ks)
          acc[mi][3 + ni] = __builtin_amdgcn_mfma_f32_16x16x32_bf16(
              af[mi][ks], b1f[ni][ks], acc[mi][3 + ni], 0, 0, 0);
    __builtin_amdgcn_s_setprio(0);
    BAR();

    // ---- p2: read A-q1 (overwrite); stage b45(t+1); MFMA (1,3..5) ----
#pragma unroll
    for (int mi = 0; mi < 2; ++mi)
#pragma unroll
      for (int ks = 0; ks < 2; ++ks)
        af[mi][ks] = *(const bf16x8*)&ldsA[(wm * 64 + 32 + mi * 16 + lr) * 64 +
                                           (((ks * 4 + kq) ^ (lr & 7)) * 8)];
    if (h1) stageB2(buf ^ 1, k0n, 4);
    __builtin_amdgcn_s_setprio(1);
#pragma unroll
    for (int mi = 0; mi < 2; ++mi)
#pragma unroll
      for (int ni = 0; ni < 3; ++ni)
#pragma unroll
        for (int ks = 0; ks < 2; ++ks)
          acc[2 + mi][3 + ni] = __builtin_amdgcn_mfma_f32_16x16x32_bf16(
              af[mi][ks], b1f[ni][ks], acc[2 + mi][3 + ni], 0, 0, 0);
    __builtin_amdgcn_s_setprio(0);
    BAR();

    // ---- p3: stage A(t+2) into CURRENT buf; MFMA (1,0..2) ----
    if (h2) stageAA(buf, (t + 2) * 64);
    __builtin_amdgcn_s_setprio(1);
#pragma unroll
    for (int mi = 0; mi < 2; ++mi)
#pragma unroll
      for (int ni = 0; ni < 3; ++ni)
#pragma unroll
        for (int ks = 0; ks < 2; ++ks)
          acc[2 + mi][ni] = __builtin_amdgcn_mfma_f32_16x16x32_bf16(
              af[mi][ks], b0f[ni][ks], acc[2 + mi][ni], 0, 0, 0);
    __builtin_amdgcn_s_setprio(0);
    if (h1) {
      if (h2) VMCNT(4);
      else VMCNT(2);
    }
    BAR();
  }

  // -------- epilogue: fused rope for z<2; v/vt unchanged --------
  bf16* Ls = &smem[0][0];  // reuse dead staging LDS, stride LSTR
  const int rb = kq * 4;
  const bool anyrope = tile_n < 2048;

  if (anyrope) {
    // stage z<2 acc columns into LDS
#pragma unroll
    for (int mi = 0; mi < 4; ++mi) {
      const int rowL = wm * 64 + mi * 16 + rb;
#pragma unroll
      for (int ni = 0; ni < 6; ++ni) {
        const int colL = wn * 96 + ni * 16 + lr;
        if (tile_n + colL < 2048) {
#pragma unroll
          for (int r2 = 0; r2 < 4; ++r2)
            Ls[(rowL + r2) * LSTR + colL] = (bf16)acc[mi][ni][r2];
        }
      }
    }
    BAR();
  }

#pragma unroll
  for (int mi = 0; mi < 4; ++mi) {
    const int row0 = tile_m + wm * 64 + mi * 16 + rb;
    const int rowL0 = wm * 64 + mi * 16 + rb;
#pragma unroll
    for (int ni = 0; ni < 6; ++ni) {
      const int colL = wn * 96 + ni * 16 + lr;
      const int col = tile_n + colL;
      const int z = col >> 10;
      const int cz = col & 1023;
      bf16* Cz = C + (size_t)z * 4194304UL;
      if (z < 2) {
        const int d = col & 127;
        const int dj = d & 63;
        const bool lohalf = d < 64;
        const int colP = colL + (lohalf ? 64 : -64);
#pragma unroll
        for (int r2 = 0; r2 < 4; ++r2) {
          float own = acc[mi][ni][r2];
          float par = (float)Ls[(rowL0 + r2) * LSTR + colP];
          float2 cv = cs[(size_t)((row0 + r2) & 2047) * 64 + dj];
          float o = lohalf ? (own * cv.x - par * cv.y)
                           : (own * cv.x + par * cv.y);
          Cz[(size_t)(row0 + r2) * 1024 + cz] = (bf16)o;
        }
      } else {
#pragma unroll
        for (int r2 = 0; r2 < 4; ++r2)
          Cz[(size_t)(row0 + r2) * 1024 + cz] = (bf16)acc[mi][ni][r2];
        const int bb2 = row0 >> 11;
        const int ss = row0 & 2047;
        bf16x4 o4;
#pragma unroll
        for (int r2 = 0; r2 < 4; ++r2) o4[r2] = (bf16)acc[mi][ni][r2];
        *(bf16x4*)&vt[(((size_t)bb2 * 8 + (cz >> 7)) * 128 + (cz & 127)) * 2048 +
                      ss] = o4;
      }
    }
  }
}

// ---------------------------------------------------------------------------
// Output projection: 128x256-tile 4-phase bf16 GEMM -> fp32 C (round 6).
// ---------------------------------------------------------------------------
#define OP_K 1024
#define OP_NT 16  // K / 64

__global__ __launch_bounds__(512, 2) void oproj_kernel(
    const bf16* __restrict__ A, const bf16* __restrict__ Bm,
    float* __restrict__ C) {
  __shared__ __align__(16) bf16 smem[2][24576];  // A[0,8192) B[8192,24576)

  const int id = blockIdx.x;
  const int wg = (id & 7) * 32 + (id >> 3);
  const int tile_n = (wg >> 5) * 256;
  const int tile_m = (wg & 31) * 128;

  const int tid = threadIdx.x;
  const int lane = tid & 63;
  const int w = tid >> 6;
  const int wm = w >> 2;  // 0..1
  const int wn = w & 3;   // 0..3
  const int lr = lane & 15;
  const int kq = lane >> 4;

  const int srow = lane >> 3;
  const int slot = lane & 7;
  const int sgo = (slot ^ srow) * 8;
  const int rloc = w * 8 + srow;

  size_t Aoff[2], Boff[4];
#pragma unroll
  for (int a = 0; a < 2; ++a)
    Aoff[a] = (size_t)(tile_m + a * 64 + rloc) * OP_K + sgo;
#pragma unroll
  for (int b = 0; b < 4; ++b) {
    const int ldsr = b * 64 + rloc;
    const int qn = ldsr >= 128 ? 1 : 0;
    const int rem = ldsr - qn * 128;
    const int wng = rem >> 5;
    const int rr = rem & 31;
    const int gcol = wng * 64 + qn * 32 + rr;
    Boff[b] = (size_t)(tile_n + gcol) * OP_K + sgo;
  }

  f32x4 acc[4][4];
#pragma unroll
  for (int i = 0; i < 4; i++)
#pragma unroll
    for (int j = 0; j < 4; j++) acc[i][j] = (f32x4){0.f, 0.f, 0.f, 0.f};

  auto stageAA = [&](int buf, int k0) {
#pragma unroll
    for (int a = 0; a < 2; ++a)
      gload_lds16(A + Aoff[a] + k0, &smem[buf][(a * 64 + w * 8) * 64]);
  };
  auto stageB2 = [&](int buf, int k0, int b0) {
#pragma unroll
    for (int u = 0; u < 2; ++u)
      gload_lds16(Bm + Boff[b0 + u] + k0,
                  &smem[buf][8192 + ((b0 + u) * 64 + w * 8) * 64]);
  };

  // prologue
  stageAA(0, 0);
  stageB2(0, 0, 0);
  stageAA(1, 64);
  stageB2(0, 0, 2);
  VMCNT(4);
  BAR();

  for (int t = 0; t < OP_NT; ++t) {
    const int buf = t & 1;
    const int k0n = (t + 1) * 64;
    const bool h1 = (t + 1 < OP_NT);
    const bool h2 = (t + 2 < OP_NT);
    const bf16* ldsA = smem[buf];
    const bf16* ldsB = smem[buf] + 8192;

    bf16x8 af[2][2], b0f[2][2], b1f[2][2];

    // ---- p0 ----
#pragma unroll
    for (int mi = 0; mi < 2; ++mi)
#pragma unroll
      for (int ks = 0; ks < 2; ++ks)
        af[mi][ks] = *(const bf16x8*)&ldsA[(wm * 64 + mi * 16 + lr) * 64 +
                                           (((ks * 4 + kq) ^ (lr & 7)) * 8)];
#pragma unroll
    for (int ni = 0; ni < 2; ++ni)
#pragma unroll
      for (int ks = 0; ks < 2; ++ks)
        b0f[ni][ks] = *(const bf16x8*)&ldsB[(wn * 32 + ni * 16 + lr) * 64 +
                                            (((ks * 4 + kq) ^ (lr & 7)) * 8)];
    if (h1) stageB2(buf ^ 1, k0n, 0);
    __builtin_amdgcn_s_setprio(1);
#pragma unroll
    for (int mi = 0; mi < 2; ++mi)
#pragma unroll
      for (int ni = 0; ni < 2; ++ni)
#pragma unroll
        for (int ks = 0; ks < 2; ++ks)
          acc[mi][ni] = __builtin_amdgcn_mfma_f32_16x16x32_bf16(
              af[mi][ks], b0f[ni][ks], acc[mi][ni], 0, 0, 0);
    __builtin_amdgcn_s_setprio(0);
    if (h1) VMCNT(4);
    else VMCNT(0);
    BAR();

    // ---- p1 ----
#pragma unroll
    for (int ni = 0; ni < 2; ++ni)
#pragma unroll
      for (int ks = 0; ks < 2; ++ks)
        b1f[ni][ks] = *(const bf16x8*)&ldsB[(128 + wn * 32 + ni * 16 + lr) * 64 +
                                            (((ks * 4 + kq) ^ (lr & 7)) * 8)];
    if (h1) stageB2(buf ^ 1, k0n, 2);
    __builtin_amdgcn_s_setprio(1);
#pragma unroll
    for (int mi = 0; mi < 2; ++mi)
#pragma unroll
      for (int ni = 0; ni < 2; ++ni)
#pragma unroll
        for (int ks = 0; ks < 2; ++ks)
          acc[mi][2 + ni] = __builtin_amdgcn_mfma_f32_16x16x32_bf16(
              af[mi][ks], b1f[ni][ks], acc[mi][2 + ni], 0, 0, 0);
    __builtin_amdgcn_s_setprio(0);
    BAR();

    // ---- p2 ----
#pragma unroll
    for (int mi = 0; mi < 2; ++mi)
#pragma unroll
      for (int ks = 0; ks < 2; ++ks)
        af[mi][ks] = *(const bf16x8*)&ldsA[(wm * 64 + 32 + mi * 16 + lr) * 64 +
                                           (((ks * 4 + kq) ^ (lr & 7)) * 8)];
    __builtin_amdgcn_s_setprio(1);
#pragma unroll
    for (int mi = 0; mi < 2; ++mi)
#pragma unroll
      for (int ni = 0; ni < 2; ++ni)
#pragma unroll
        for (int ks = 0; ks < 2; ++ks)
          acc[2 + mi][2 + ni] = __builtin_amdgcn_mfma_f32_16x16x32_bf16(
              af[mi][ks], b1f[ni][ks], acc[2 + mi][2 + ni], 0, 0, 0);
    __builtin_amdgcn_s_setprio(0);
    BAR();

    // ---- p3 ----
    if (h2) stageAA(buf, (t + 2) * 64);
    __builtin_amdgcn_s_setprio(1);
#pragma unroll
    for (int mi = 0; mi < 2; ++mi)
#pragma unroll
      for (int ni = 0; ni < 2; ++ni)
#pragma unroll
        for (int ks = 0; ks < 2; ++ks)
          acc[2 + mi][ni] = __builtin_amdgcn_mfma_f32_16x16x32_bf16(
              af[mi][ks], b0f[ni][ks], acc[2 + mi][ni], 0, 0, 0);
    __builtin_amdgcn_s_setprio(0);
    if (h1) {
      if (h2) VMCNT(4);
      else VMCNT(2);
    }
    BAR();
  }

  // epilogue: fp32 C
  const int rb = kq * 4;
#pragma unroll
  for (int i = 0; i < 4; ++i) {
    const int row0 = tile_m + wm * 64 + (i >> 1) * 32 + (i & 1) * 16 + rb;
#pragma unroll
    for (int j = 0; j < 4; ++j) {
      const int col = tile_n + wn * 64 + (j >> 1) * 32 + (j & 1) * 16 + lr;
#pragma unroll
      for (int r2 = 0; r2 < 4; ++r2)
        C[(size_t)(row0 + r2) * 2048 + col] = acc[i][j][r2];
    }
  }
}

// ---------------------------------------------------------------------------
// MFMA banded-decay attention (round 6; q/kk arrive pre-roped).
// ---------------------------------------------------------------------------
__global__ __launch_bounds__(256) void attn_mfma_kernel(
    const bf16* __restrict__ q, const bf16* __restrict__ k,
    const bf16* __restrict__ vt, const float* __restrict__ beta,
    const float* __restrict__ la_mean, bf16* __restrict__ outb) {
  const int s0 = blockIdx.x * 64;
  const int h = blockIdx.y;
  const int b = blockIdx.z;
  const int tid = threadIdx.x;
  const int w = tid >> 6;
  const int lane = tid & 63;
  const int lr = lane & 15;
  const int kq = lane >> 4;  // quad
  const float la = la_mean[h];

  __shared__ __align__(16) bf16 Ps[4][2][16][72];

  const int sg = s0 + w * 16;
  const size_t qbase =
      ((size_t)b * S_LEN + (sg + lr)) * INNER_DIM + h * 128 + kq * 8;
  bf16x8 aq[4];
#pragma unroll
  for (int ks = 0; ks < 4; ks++)
    aq[ks] = *(const bf16x8*)&q[qbase + ks * 32];

  f32x4 O[8];
#pragma unroll
  for (int en = 0; en < 8; en++) O[en] = (f32x4){0.f, 0.f, 0.f, 0.f};

  const size_t kbase = (size_t)b * S_LEN * INNER_DIM + h * 128 + kq * 8;
  const size_t vtbase = ((size_t)b * 8 + h) * 128 * 2048;

#pragma unroll
  for (int tile = 0; tile < 2; tile++) {
    const int tb = s0 - 64 + tile * 64;
    f32x4 sc[4];
#pragma unroll
    for (int nt = 0; nt < 4; nt++) sc[nt] = (f32x4){0.f, 0.f, 0.f, 0.f};
#pragma unroll
    for (int nt = 0; nt < 4; nt++) {
      int t = tb + nt * 16 + lr;
      int tc = t > 0 ? t : 0;
#pragma unroll
      for (int ks = 0; ks < 4; ks++) {
        bf16x8 bk = *(const bf16x8*)&k[kbase + (size_t)tc * INNER_DIM + ks * 32];
        sc[nt] = __builtin_amdgcn_mfma_f32_16x16x32_bf16(aq[ks], bk, sc[nt],
                                                         0, 0, 0);
      }
    }
#pragma unroll
    for (int nt = 0; nt < 4; nt++) {
      int t = tb + nt * 16 + lr;
      int tc = t > 0 ? t : 0;
      float bt = beta[((size_t)b * S_LEN + tc) * 8 + h];
#pragma unroll
      for (int reg = 0; reg < 4; reg++) {
        int qrow = sg + kq * 4 + reg;
        int td = qrow - t;
        float wgt = 0.0f;
        if (t >= 0 && td >= 0 && td < 64)
          wgt = sc[nt][reg] * __expf((float)td * la) * bt;
        Ps[w][tile][kq * 4 + reg][nt * 16 + lr] = (bf16)wgt;
      }
    }
    __syncthreads();
    bf16x8 ap[2];
#pragma unroll
    for (int ks2 = 0; ks2 < 2; ks2++)
      ap[ks2] = *(const bf16x8*)&Ps[w][tile][lr][ks2 * 32 + kq * 8];
#pragma unroll
    for (int en = 0; en < 8; en++) {
#pragma unroll
      for (int ks2 = 0; ks2 < 2; ks2++) {
        int t0f = tb + ks2 * 32 + kq * 8;
        int tcf = t0f > 0 ? t0f : 0;
        bf16x8 bv = *(const bf16x8*)&vt[vtbase + (size_t)(en * 16 + lr) * 2048 +
                                        tcf];
        O[en] = __builtin_amdgcn_mfma_f32_16x16x32_bf16(ap[ks2], bv, O[en], 0,
                                                        0, 0);
      }
    }
  }
  const size_t obase = (size_t)b * S_LEN * INNER_DIM + h * 128;
#pragma unroll
  for (int en = 0; en < 8; en++) {
#pragma unroll
    for (int reg = 0; reg < 4; reg++) {
      int qrow = sg + kq * 4 + reg;
      outb[obase + (size_t)qrow * INNER_DIM + en * 16 + lr] =
          (bf16)O[en][reg];
    }
  }
}

// ---------------------------------------------------------------------------
// Stage 1: partial state per 32-step chunk (round 6; kk pre-roped).
// ---------------------------------------------------------------------------
__global__ __launch_bounds__(256) void state_partial_kernel(
    const bf16* __restrict__ k, const bf16* __restrict__ v,
    const float* __restrict__ beta, const float* __restrict__ la_d,
    float* __restrict__ part) {
  const int bh = blockIdx.x;
  const int chunk = blockIdx.y;
  const int b = bh >> 3, h = bh & 7;
  const int t0 = S_LEN - 512 + chunk * 32;
  const int tid = threadIdx.x;
  const int d = tid >> 1;
  const int eh = (tid & 1) * 64;

  __shared__ float ks[32][128];
  __shared__ float vsm[32][128];
  __shared__ float bs[32];

  const size_t bh_off = ((size_t)b * S_LEN) * INNER_DIM + (size_t)h * 128;
  for (int u = tid; u < 32 * 16; u += 256) {
    int r = u >> 4, c8 = (u & 15) * 8;
    bf16x8 kv = *(const bf16x8*)&k[bh_off + (size_t)(t0 + r) * INNER_DIM + c8];
    bf16x8 vv = *(const bf16x8*)&v[bh_off + (size_t)(t0 + r) * INNER_DIM + c8];
#pragma unroll
    for (int j = 0; j < 8; j++) {
      ks[r][c8 + j] = (float)kv[j];
      vsm[r][c8 + j] = (float)vv[j];
    }
  }
  if (tid < 32) bs[tid] = beta[((size_t)b * S_LEN + t0 + tid) * 8 + h];
  __syncthreads();

  const float lad = la_d[h * 128 + d];
  float acc[64];
#pragma unroll
  for (int e = 0; e < 64; e++) acc[e] = 0.0f;

  for (int tl = 0; tl < 32; tl++) {
    int m = (S_LEN - 1) - (t0 + tl);
    float f = __expf((float)m * lad);
    float coef = bs[tl] * ks[tl][d] * f;
    if (coef != 0.0f) {
#pragma unroll
      for (int e = 0; e < 64; e += 4) {
        float4 vv = *(const float4*)&vsm[tl][eh + e];
        acc[e + 0] = fmaf(coef, vv.x, acc[e + 0]);
        acc[e + 1] = fmaf(coef, vv.y, acc[e + 1]);
        acc[e + 2] = fmaf(coef, vv.z, acc[e + 2]);
        acc[e + 3] = fmaf(coef, vv.w, acc[e + 3]);
      }
    }
  }
  float* pp = part + (((size_t)chunk * 16 + bh) * 16384 + (size_t)d * 128 + eh);
#pragma unroll
  for (int e = 0; e < 64; e += 4) {
    float4 o = {acc[e + 0], acc[e + 1], acc[e + 2], acc[e + 3]};
    *(float4*)&pp[e] = o;
  }
}

// ---------------------------------------------------------------------------
// Stage 2: sum the 16 chunk partials into the final state (round 6).
// ---------------------------------------------------------------------------
__global__ __launch_bounds__(256) void state_reduce_kernel(
    const float* __restrict__ part, float* __restrict__ state) {
  size_t off = ((size_t)blockIdx.x * 256 + threadIdx.x) * 4;
  float4 s = {0.f, 0.f, 0.f, 0.f};
#pragma unroll
  for (int c = 0; c < 16; c++) {
    float4 p = *(const float4*)&part[(size_t)c * 262144 + off];
    s.x += p.x; s.y += p.y; s.z += p.z; s.w += p.w;
  }
  *(float4*)&state[off] = s;
}

// ---------------------------------------------------------------------------
extern "C" void kernel_launch(void* const* d_in, const int* in_sizes, int n_in,
                              void* d_out, int out_size, void* d_ws,
                              size_t ws_size, hipStream_t stream) {
  const float* x = (const float*)d_in[0];
  const float* Wq = (const float*)d_in[1];
  const float* Wk = (const float*)d_in[2];
  const float* Wv = (const float*)d_in[3];
  const float* Wo = (const float*)d_in[4];
  const float* Wb = (const float*)d_in[5];
  const float* bb = (const float*)d_in[6];
  const float* alog = (const float*)d_in[7];
  float* out = (float*)d_out;

  char* ws = (char*)d_ws;
  bf16* xb = (bf16*)(ws);                      // 16 MB
  float* part = (float*)(ws);                  // reuses xb after QKV GEMM
  bf16* wqkvb = (bf16*)(ws + 16777216UL);      // 12 MB
  bf16* wob = (bf16*)(ws + 29360128UL);        // 4 MB
  bf16* q = (bf16*)(ws + 33554432UL);          // 8 MB
  bf16* kk = (bf16*)(ws + 41943040UL);         // 8 MB
  bf16* vv = (bf16*)(ws + 50331648UL);         // 8 MB
  bf16* attnb = (bf16*)(ws + 58720256UL);      // 8 MB
  bf16* vt = (bf16*)(ws + 67108864UL);         // 8 MB (V transposed)
  float* beta = (float*)(ws + 75497472UL);     // 128 KB
  float* la_mean = (float*)(ws + 75628544UL);  // 32 B
  float* la_d = (float*)(ws + 75628800UL);     // 4 KB
  float2* cs = (float2*)(ws + 75632896UL);     // 1 MB rope table

  prep_kernel<<<9736, 256, 0, stream>>>(x, Wq, Wk, Wv, Wo, Wb, bb, alog,
                                        wqkvb, wob, xb, beta, la_mean, la_d,
                                        cs);
  // QKV GEMM with fused RoPE epilogue -> roped q/kk, vv (+ vt)
  qkv_gemm8p_kernel<<<256, 512, 0, stream>>>(xb, wqkvb, q, vt, cs);
  attn_mfma_kernel<<<dim3(S_LEN / 64, NHEADS, BATCH), 256, 0, stream>>>(
      q, kk, vt, beta, la_mean, attnb);
  state_partial_kernel<<<dim3(16, 16), 256, 0, stream>>>(kk, vv, beta, la_d,
                                                         part);
  state_reduce_kernel<<<256, 256, 0, stream>>>(part, out + 8388608);
  oproj_kernel<<<256, 512, 0, stream>>>(attnb, wob, out);
}

// Round 10
// 257.298 us; speedup vs baseline: 1.0648x; 1.0149x over previous
//
#include <hip/hip_runtime.h>
#include <hip/hip_bf16.h>
#include <cstdint>
#include <cstddef>

// Problem constants
#define S_LEN 2048
#define DMODEL 2048
#define NHEADS 8
#define DHEAD 128
#define INNER_DIM 1024
#define BATCH 2

typedef __bf16 bf16;
typedef __bf16 bf16x8 __attribute__((ext_vector_type(8)));
typedef __bf16 bf16x4 __attribute__((ext_vector_type(4)));
typedef float f32x4 __attribute__((ext_vector_type(4)));

#define VMCNT(n) asm volatile("s_waitcnt vmcnt(" #n ")" ::: "memory")
#define BAR()                                \
  do {                                       \
    asm volatile("" ::: "memory");           \
    __builtin_amdgcn_s_barrier();            \
    asm volatile("" ::: "memory");           \
  } while (0)

__device__ __forceinline__ void gload_lds16(const void* g, void* l) {
  __builtin_amdgcn_global_load_lds(
      (const __attribute__((address_space(1))) void*)g,
      (__attribute__((address_space(3))) void*)l, 16, 0, 0);
}

__device__ __forceinline__ float sigmoidf_(float x) {
  return 1.0f / (1.0f + expf(-x));
}

// ---------------------------------------------------------------------------
// Fused prep kernel, range-dispatched on blockIdx.x (unchanged).
// ---------------------------------------------------------------------------
__global__ __launch_bounds__(256) void prep_kernel(
    const float* __restrict__ x, const float* __restrict__ wq,
    const float* __restrict__ wk, const float* __restrict__ wv,
    const float* __restrict__ wo, const float* __restrict__ Wb,
    const float* __restrict__ bbias, const float* __restrict__ alpha_log,
    bf16* __restrict__ wqkvb, bf16* __restrict__ wob, bf16* __restrict__ xb,
    float* __restrict__ beta, float* __restrict__ la_mean,
    float* __restrict__ la_d, float2* __restrict__ cs) {
  const int bid = blockIdx.x;
  const int tid = threadIdx.x;

  if (bid < 8192) {
    size_t i4 = ((size_t)bid * 256 + tid) * 4;
    const float* src;
    bf16* dst;
    size_t off;
    if (i4 < 2097152UL)       { src = wq; dst = wqkvb;           off = i4; }
    else if (i4 < 4194304UL)  { src = wk; dst = wqkvb + 2097152; off = i4 - 2097152UL; }
    else if (i4 < 6291456UL)  { src = wv; dst = wqkvb + 4194304; off = i4 - 4194304UL; }
    else                      { src = wo; dst = wob;             off = i4 - 6291456UL; }
    float4 v = *(const float4*)(src + off);
    bf16x4 o;
    o[0] = (bf16)v.x; o[1] = (bf16)v.y; o[2] = (bf16)v.z; o[3] = (bf16)v.w;
    *(bf16x4*)(dst + off) = o;
  } else if (bid < 9216) {
    const int n = (bid - 8192) * 4 + (tid >> 6);
    const int lane = tid & 63;
    float acc[8];
#pragma unroll
    for (int h = 0; h < 8; h++) acc[h] = 0.0f;
    const float4* x4 = (const float4*)(x + (size_t)n * DMODEL);
    bf16* xbr = xb + (size_t)n * DMODEL;
    for (int d4 = lane; d4 < DMODEL / 4; d4 += 64) {
      float4 xv = x4[d4];
      bf16x4 o;
      o[0] = (bf16)xv.x; o[1] = (bf16)xv.y; o[2] = (bf16)xv.z; o[3] = (bf16)xv.w;
      *(bf16x4*)(xbr + d4 * 4) = o;
#pragma unroll
      for (int h = 0; h < 8; h++) {
        float4 wv2 = ((const float4*)(Wb + (size_t)h * DMODEL))[d4];
        acc[h] += xv.x * wv2.x + xv.y * wv2.y + xv.z * wv2.z + xv.w * wv2.w;
      }
    }
#pragma unroll
    for (int off = 32; off; off >>= 1)
#pragma unroll
      for (int h = 0; h < 8; h++) acc[h] += __shfl_down(acc[h], off);
    if (lane == 0) {
#pragma unroll
      for (int h = 0; h < 8; h++)
        beta[(size_t)n * 8 + h] = sigmoidf_(acc[h] + bbias[h]);
    }
  } else if (bid < 9728) {
    int idx = (bid - 9216) * 256 + tid;  // < 131072 = 2048*64
    int s = idx >> 6, j = idx & 63;
    float f = (float)s * expf(-(float)j * (9.210340371976184f / 64.0f));
    float sn, c;
    sincosf(f, &sn, &c);
    cs[idx] = make_float2(c, sn);
  } else {
    if (tid >= 64) return;
    const int h = bid - 9728;
    const int lane = tid;
    float a1 = sigmoidf_(alpha_log[h * 128 + lane]);
    float a2 = sigmoidf_(alpha_log[h * 128 + 64 + lane]);
    la_d[h * 128 + lane] = logf(a1);
    la_d[h * 128 + 64 + lane] = logf(a2);
    float s = a1 + a2;
    for (int off = 32; off; off >>= 1) s += __shfl_down(s, off);
    if (lane == 0) la_mean[h] = logf(fmaxf(s * (1.0f / 128.0f), 1e-6f));
  }
}

// ---------------------------------------------------------------------------
// QKV projection with fused RoPE epilogue (round-9 verified, 61 us).
// ---------------------------------------------------------------------------
#define QKV_K 2048
#define QKV_NT 32  // K / 64
#define LSTR 392   // epilogue LDS stride (elems)

__global__ __launch_bounds__(512, 2) void qkv_gemm8p_kernel(
    const bf16* __restrict__ A, const bf16* __restrict__ Bm,
    bf16* __restrict__ C, bf16* __restrict__ vt,
    const float2* __restrict__ cs) {
  __shared__ __align__(16) bf16 smem[2][32768];  // buf: A[0,8192) B[8192,32768)

  const int id = blockIdx.x;
  const int wg = (id & 7) * 32 + (id >> 3);
  const int tile_n = (wg >> 5) * 384;
  const int tile_m = (wg & 31) * 128;

  const int tid = threadIdx.x;
  const int lane = tid & 63;
  const int w = tid >> 6;
  const int wm = w >> 2;  // 0..1 -> rows wm*64
  const int wn = w & 3;   // 0..3 -> cols wn*96
  const int lr = lane & 15;
  const int kq = lane >> 4;

  const int srow = lane >> 3;
  const int slot = lane & 7;
  const int sgo = (slot ^ srow) * 8;
  const int rloc = w * 8 + srow;

  size_t Aoff[2], Boff[6];
#pragma unroll
  for (int a = 0; a < 2; ++a)
    Aoff[a] = (size_t)(tile_m + a * 64 + rloc) * QKV_K + sgo;
#pragma unroll
  for (int b = 0; b < 6; ++b) {
    const int ldsr = b * 64 + rloc;
    const int qn = ldsr >= 192 ? 1 : 0;
    const int rem = ldsr - qn * 192;
    const int wng = rem / 48;
    const int rr = rem - wng * 48;
    const int gcol = wng * 96 + qn * 48 + rr;
    Boff[b] = (size_t)(tile_n + gcol) * QKV_K + sgo;
  }

  f32x4 acc[4][6];
#pragma unroll
  for (int i = 0; i < 4; i++)
#pragma unroll
    for (int j = 0; j < 6; j++) acc[i][j] = (f32x4){0.f, 0.f, 0.f, 0.f};

  auto stageAA = [&](int buf, int k0) {
#pragma unroll
    for (int a = 0; a < 2; ++a)
      gload_lds16(A + Aoff[a] + k0, &smem[buf][(a * 64 + w * 8) * 64]);
  };
  auto stageB2 = [&](int buf, int k0, int b0) {
#pragma unroll
    for (int u = 0; u < 2; ++u)
      gload_lds16(Bm + Boff[b0 + u] + k0,
                  &smem[buf][8192 + ((b0 + u) * 64 + w * 8) * 64]);
  };

  // prologue (order matters for the ledger)
  stageAA(0, 0);
  stageB2(0, 0, 0);
  stageB2(0, 0, 2);
  stageAA(1, 64);
  stageB2(0, 0, 4);
  VMCNT(4);
  BAR();

  for (int t = 0; t < QKV_NT; ++t) {
    const int buf = t & 1;
    const int k0n = (t + 1) * 64;
    const bool h1 = (t + 1 < QKV_NT);
    const bool h2 = (t + 2 < QKV_NT);
    const bf16* ldsA = smem[buf];
    const bf16* ldsB = smem[buf] + 8192;

    bf16x8 af[2][2], b0f[3][2], b1f[3][2];

    // ---- p0: read A-q0 + B-q0; stage b01(t+1); MFMA (0,0..2) ----
#pragma unroll
    for (int mi = 0; mi < 2; ++mi)
#pragma unroll
      for (int ks = 0; ks < 2; ++ks)
        af[mi][ks] = *(const bf16x8*)&ldsA[(wm * 64 + mi * 16 + lr) * 64 +
                                           (((ks * 4 + kq) ^ (lr & 7)) * 8)];
#pragma unroll
    for (int ni = 0; ni < 3; ++ni)
#pragma unroll
      for (int ks = 0; ks < 2; ++ks)
        b0f[ni][ks] = *(const bf16x8*)&ldsB[(wn * 48 + ni * 16 + lr) * 64 +
                                            (((ks * 4 + kq) ^ (lr & 7)) * 8)];
    if (h1) stageB2(buf ^ 1, k0n, 0);
    __builtin_amdgcn_s_setprio(1);
#pragma unroll
    for (int mi = 0; mi < 2; ++mi)
#pragma unroll
      for (int ni = 0; ni < 3; ++ni)
#pragma unroll
        for (int ks = 0; ks < 2; ++ks)
          acc[mi][ni] = __builtin_amdgcn_mfma_f32_16x16x32_bf16(
              af[mi][ks], b0f[ni][ks], acc[mi][ni], 0, 0, 0);
    __builtin_amdgcn_s_setprio(0);
    if (h1) VMCNT(4);
    else VMCNT(0);
    BAR();

    // ---- p1: read B-q1; stage b23(t+1); MFMA (0,3..5) ----
#pragma unroll
    for (int ni = 0; ni < 3; ++ni)
#pragma unroll
      for (int ks = 0; ks < 2; ++ks)
        b1f[ni][ks] = *(const bf16x8*)&ldsB[(192 + wn * 48 + ni * 16 + lr) * 64 +
                                            (((ks * 4 + kq) ^ (lr & 7)) * 8)];
    if (h1) stageB2(buf ^ 1, k0n, 2);
    __builtin_amdgcn_s_setprio(1);
#pragma unroll
    for (int mi = 0; mi < 2; ++mi)
#pragma unroll
      for (int ni = 0; ni < 3; ++ni)
#pragma unroll
        for (int ks = 0; ks < 2; ++ks)
          acc[mi][3 + ni] = __builtin_amdgcn_mfma_f32_16x16x32_bf16(
              af[mi][ks], b1f[ni][ks], acc[mi][3 + ni], 0, 0, 0);
    __builtin_amdgcn_s_setprio(0);
    BAR();

    // ---- p2: read A-q1 (overwrite); stage b45(t+1); MFMA (1,3..5) ----
#pragma unroll
    for (int mi = 0; mi < 2; ++mi)
#pragma unroll
      for (int ks = 0; ks < 2; ++ks)
        af[mi][ks] = *(const bf16x8*)&ldsA[(wm * 64 + 32 + mi * 16 + lr) * 64 +
                                           (((ks * 4 + kq) ^ (lr & 7)) * 8)];
    if (h1) stageB2(buf ^ 1, k0n, 4);
    __builtin_amdgcn_s_setprio(1);
#pragma unroll
    for (int mi = 0; mi < 2; ++mi)
#pragma unroll
      for (int ni = 0; ni < 3; ++ni)
#pragma unroll
        for (int ks = 0; ks < 2; ++ks)
          acc[2 + mi][3 + ni] = __builtin_amdgcn_mfma_f32_16x16x32_bf16(
              af[mi][ks], b1f[ni][ks], acc[2 + mi][3 + ni], 0, 0, 0);
    __builtin_amdgcn_s_setprio(0);
    BAR();

    // ---- p3: stage A(t+2) into CURRENT buf; MFMA (1,0..2) ----
    if (h2) stageAA(buf, (t + 2) * 64);
    __builtin_amdgcn_s_setprio(1);
#pragma unroll
    for (int mi = 0; mi < 2; ++mi)
#pragma unroll
      for (int ni = 0; ni < 3; ++ni)
#pragma unroll
        for (int ks = 0; ks < 2; ++ks)
          acc[2 + mi][ni] = __builtin_amdgcn_mfma_f32_16x16x32_bf16(
              af[mi][ks], b0f[ni][ks], acc[2 + mi][ni], 0, 0, 0);
    __builtin_amdgcn_s_setprio(0);
    if (h1) {
      if (h2) VMCNT(4);
      else VMCNT(2);
    }
    BAR();
  }

  // -------- epilogue: fused rope for z<2; v/vt unchanged --------
  bf16* Ls = &smem[0][0];  // reuse dead staging LDS, stride LSTR
  const int rb = kq * 4;
  const bool anyrope = tile_n < 2048;

  if (anyrope) {
#pragma unroll
    for (int mi = 0; mi < 4; ++mi) {
      const int rowL = wm * 64 + mi * 16 + rb;
#pragma unroll
      for (int ni = 0; ni < 6; ++ni) {
        const int colL = wn * 96 + ni * 16 + lr;
        if (tile_n + colL < 2048) {
#pragma unroll
          for (int r2 = 0; r2 < 4; ++r2)
            Ls[(rowL + r2) * LSTR + colL] = (bf16)acc[mi][ni][r2];
        }
      }
    }
    BAR();
  }

#pragma unroll
  for (int mi = 0; mi < 4; ++mi) {
    const int row0 = tile_m + wm * 64 + mi * 16 + rb;
    const int rowL0 = wm * 64 + mi * 16 + rb;
#pragma unroll
    for (int ni = 0; ni < 6; ++ni) {
      const int colL = wn * 96 + ni * 16 + lr;
      const int col = tile_n + colL;
      const int z = col >> 10;
      const int cz = col & 1023;
      bf16* Cz = C + (size_t)z * 4194304UL;
      if (z < 2) {
        const int d = col & 127;
        const int dj = d & 63;
        const bool lohalf = d < 64;
        const int colP = colL + (lohalf ? 64 : -64);
#pragma unroll
        for (int r2 = 0; r2 < 4; ++r2) {
          float own = acc[mi][ni][r2];
          float par = (float)Ls[(rowL0 + r2) * LSTR + colP];
          float2 cv = cs[(size_t)((row0 + r2) & 2047) * 64 + dj];
          float o = lohalf ? (own * cv.x - par * cv.y)
                           : (own * cv.x + par * cv.y);
          Cz[(size_t)(row0 + r2) * 1024 + cz] = (bf16)o;
        }
      } else {
#pragma unroll
        for (int r2 = 0; r2 < 4; ++r2)
          Cz[(size_t)(row0 + r2) * 1024 + cz] = (bf16)acc[mi][ni][r2];
        const int bb2 = row0 >> 11;
        const int ss = row0 & 2047;
        bf16x4 o4;
#pragma unroll
        for (int r2 = 0; r2 < 4; ++r2) o4[r2] = (bf16)acc[mi][ni][r2];
        *(bf16x4*)&vt[(((size_t)bb2 * 8 + (cz >> 7)) * 128 + (cz & 127)) * 2048 +
                      ss] = o4;
      }
    }
  }
}

// ---------------------------------------------------------------------------
// Output projection (bid<256) + state reduce (bid>=256), fused launch.
// GEMM core unchanged.
// ---------------------------------------------------------------------------
#define OP_K 1024
#define OP_NT 16  // K / 64

__global__ __launch_bounds__(512, 2) void oproj_kernel(
    const bf16* __restrict__ A, const bf16* __restrict__ Bm,
    float* __restrict__ C, const float* __restrict__ part) {
  __shared__ __align__(16) bf16 smem[2][24576];  // A[0,8192) B[8192,24576)

  const int id = blockIdx.x;
  const int tid = threadIdx.x;

  if (id >= 256) {
    // ---- state reduce: sum 16 chunk partials ----
    size_t off = (((size_t)id - 256) * 512 + tid) * 4;
    float4 s = {0.f, 0.f, 0.f, 0.f};
#pragma unroll
    for (int c = 0; c < 16; c++) {
      float4 p = *(const float4*)&part[(size_t)c * 262144 + off];
      s.x += p.x; s.y += p.y; s.z += p.z; s.w += p.w;
    }
    *(float4*)&C[8388608UL + off] = s;
    return;
  }

  const int wg = (id & 7) * 32 + (id >> 3);
  const int tile_n = (wg >> 5) * 256;
  const int tile_m = (wg & 31) * 128;

  const int lane = tid & 63;
  const int w = tid >> 6;
  const int wm = w >> 2;  // 0..1
  const int wn = w & 3;   // 0..3
  const int lr = lane & 15;
  const int kq = lane >> 4;

  const int srow = lane >> 3;
  const int slot = lane & 7;
  const int sgo = (slot ^ srow) * 8;
  const int rloc = w * 8 + srow;

  size_t Aoff[2], Boff[4];
#pragma unroll
  for (int a = 0; a < 2; ++a)
    Aoff[a] = (size_t)(tile_m + a * 64 + rloc) * OP_K + sgo;
#pragma unroll
  for (int b = 0; b < 4; ++b) {
    const int ldsr = b * 64 + rloc;
    const int qn = ldsr >= 128 ? 1 : 0;
    const int rem = ldsr - qn * 128;
    const int wng = rem >> 5;
    const int rr = rem & 31;
    const int gcol = wng * 64 + qn * 32 + rr;
    Boff[b] = (size_t)(tile_n + gcol) * OP_K + sgo;
  }

  f32x4 acc[4][4];
#pragma unroll
  for (int i = 0; i < 4; i++)
#pragma unroll
    for (int j = 0; j < 4; j++) acc[i][j] = (f32x4){0.f, 0.f, 0.f, 0.f};

  auto stageAA = [&](int buf, int k0) {
#pragma unroll
    for (int a = 0; a < 2; ++a)
      gload_lds16(A + Aoff[a] + k0, &smem[buf][(a * 64 + w * 8) * 64]);
  };
  auto stageB2 = [&](int buf, int k0, int b0) {
#pragma unroll
    for (int u = 0; u < 2; ++u)
      gload_lds16(Bm + Boff[b0 + u] + k0,
                  &smem[buf][8192 + ((b0 + u) * 64 + w * 8) * 64]);
  };

  // prologue
  stageAA(0, 0);
  stageB2(0, 0, 0);
  stageAA(1, 64);
  stageB2(0, 0, 2);
  VMCNT(4);
  BAR();

  for (int t = 0; t < OP_NT; ++t) {
    const int buf = t & 1;
    const int k0n = (t + 1) * 64;
    const bool h1 = (t + 1 < OP_NT);
    const bool h2 = (t + 2 < OP_NT);
    const bf16* ldsA = smem[buf];
    const bf16* ldsB = smem[buf] + 8192;

    bf16x8 af[2][2], b0f[2][2], b1f[2][2];

    // ---- p0 ----
#pragma unroll
    for (int mi = 0; mi < 2; ++mi)
#pragma unroll
      for (int ks = 0; ks < 2; ++ks)
        af[mi][ks] = *(const bf16x8*)&ldsA[(wm * 64 + mi * 16 + lr) * 64 +
                                           (((ks * 4 + kq) ^ (lr & 7)) * 8)];
#pragma unroll
    for (int ni = 0; ni < 2; ++ni)
#pragma unroll
      for (int ks = 0; ks < 2; ++ks)
        b0f[ni][ks] = *(const bf16x8*)&ldsB[(wn * 32 + ni * 16 + lr) * 64 +
                                            (((ks * 4 + kq) ^ (lr & 7)) * 8)];
    if (h1) stageB2(buf ^ 1, k0n, 0);
    __builtin_amdgcn_s_setprio(1);
#pragma unroll
    for (int mi = 0; mi < 2; ++mi)
#pragma unroll
      for (int ni = 0; ni < 2; ++ni)
#pragma unroll
        for (int ks = 0; ks < 2; ++ks)
          acc[mi][ni] = __builtin_amdgcn_mfma_f32_16x16x32_bf16(
              af[mi][ks], b0f[ni][ks], acc[mi][ni], 0, 0, 0);
    __builtin_amdgcn_s_setprio(0);
    if (h1) VMCNT(4);
    else VMCNT(0);
    BAR();

    // ---- p1 ----
#pragma unroll
    for (int ni = 0; ni < 2; ++ni)
#pragma unroll
      for (int ks = 0; ks < 2; ++ks)
        b1f[ni][ks] = *(const bf16x8*)&ldsB[(128 + wn * 32 + ni * 16 + lr) * 64 +
                                            (((ks * 4 + kq) ^ (lr & 7)) * 8)];
    if (h1) stageB2(buf ^ 1, k0n, 2);
    __builtin_amdgcn_s_setprio(1);
#pragma unroll
    for (int mi = 0; mi < 2; ++mi)
#pragma unroll
      for (int ni = 0; ni < 2; ++ni)
#pragma unroll
        for (int ks = 0; ks < 2; ++ks)
          acc[mi][2 + ni] = __builtin_amdgcn_mfma_f32_16x16x32_bf16(
              af[mi][ks], b1f[ni][ks], acc[mi][2 + ni], 0, 0, 0);
    __builtin_amdgcn_s_setprio(0);
    BAR();

    // ---- p2 ----
#pragma unroll
    for (int mi = 0; mi < 2; ++mi)
#pragma unroll
      for (int ks = 0; ks < 2; ++ks)
        af[mi][ks] = *(const bf16x8*)&ldsA[(wm * 64 + 32 + mi * 16 + lr) * 64 +
                                           (((ks * 4 + kq) ^ (lr & 7)) * 8)];
    __builtin_amdgcn_s_setprio(1);
#pragma unroll
    for (int mi = 0; mi < 2; ++mi)
#pragma unroll
      for (int ni = 0; ni < 2; ++ni)
#pragma unroll
        for (int ks = 0; ks < 2; ++ks)
          acc[2 + mi][2 + ni] = __builtin_amdgcn_mfma_f32_16x16x32_bf16(
              af[mi][ks], b1f[ni][ks], acc[2 + mi][2 + ni], 0, 0, 0);
    __builtin_amdgcn_s_setprio(0);
    BAR();

    // ---- p3 ----
    if (h2) stageAA(buf, (t + 2) * 64);
    __builtin_amdgcn_s_setprio(1);
#pragma unroll
    for (int mi = 0; mi < 2; ++mi)
#pragma unroll
      for (int ni = 0; ni < 2; ++ni)
#pragma unroll
        for (int ks = 0; ks < 2; ++ks)
          acc[2 + mi][ni] = __builtin_amdgcn_mfma_f32_16x16x32_bf16(
              af[mi][ks], b0f[ni][ks], acc[2 + mi][ni], 0, 0, 0);
    __builtin_amdgcn_s_setprio(0);
    if (h1) {
      if (h2) VMCNT(4);
      else VMCNT(2);
    }
    BAR();
  }

  // epilogue: fp32 C
  const int rb = kq * 4;
#pragma unroll
  for (int i = 0; i < 4; ++i) {
    const int row0 = tile_m + wm * 64 + (i >> 1) * 32 + (i & 1) * 16 + rb;
#pragma unroll
    for (int j = 0; j < 4; ++j) {
      const int col = tile_n + wn * 64 + (j >> 1) * 32 + (j & 1) * 16 + lr;
#pragma unroll
      for (int r2 = 0; r2 < 4; ++r2)
        C[(size_t)(row0 + r2) * 2048 + col] = acc[i][j][r2];
    }
  }
}

// ---------------------------------------------------------------------------
// MFMA banded-decay attention, ROUND-10: per-wave WINDOW-ALIGNED schedule.
// Each wave owns rows [sg, sg+16); valid t window is (sg-64, sg+16) = 80
// cols. Old code computed the block-aligned 128-col window -> every wave
// wasted 3/8 QK^T nt-tiles (fully masked) + ~37% of PV/loads/exp.
// New: 5 nt tiles from tb0 = sg-64 (80 cols); Ps[16][104] with cols
// [80,96) zero-filled; PV over 3 ks2 windows (third covers the zero pad;
// vt row clamped to [0,2040] -- unclamped would read OOB at sg=2032).
// Ps is wave-private -> no __syncthreads; explicit lgkmcnt(0)+sched_barrier
// (rule #18) orders write->read within the wave. Math is element-identical
// (same masking), so absmax is unchanged.
// MFMA/wave 64->44, k-loads 32->20, exp 32->20, beta gathers 8->5.
// ---------------------------------------------------------------------------
__global__ __launch_bounds__(256) void attn_mfma_kernel(
    const bf16* __restrict__ q, const bf16* __restrict__ k,
    const bf16* __restrict__ vt, const float* __restrict__ beta,
    const float* __restrict__ la_mean, bf16* __restrict__ outb) {
  const int s0 = blockIdx.x * 64;
  const int h = blockIdx.y;
  const int b = blockIdx.z;
  const int tid = threadIdx.x;
  const int w = tid >> 6;
  const int lane = tid & 63;
  const int lr = lane & 15;
  const int kq = lane >> 4;  // quad
  const float la = la_mean[h];

  __shared__ __align__(16) bf16 Ps[4][16][104];

  const int sg = s0 + w * 16;   // wave's first q row
  const int tb0 = sg - 64;      // wave's window start

  const size_t qbase =
      ((size_t)b * S_LEN + (sg + lr)) * INNER_DIM + h * 128 + kq * 8;
  bf16x8 aq[4];
#pragma unroll
  for (int ks = 0; ks < 4; ks++)
    aq[ks] = *(const bf16x8*)&q[qbase + ks * 32];

  const size_t kbase = (size_t)b * S_LEN * INNER_DIM + h * 128 + kq * 8;
  const size_t vtbase = ((size_t)b * 8 + h) * 128 * 2048;

  // ---- QK^T: 5 nt tiles covering t in [sg-64, sg+16) ----
  f32x4 sc[5];
#pragma unroll
  for (int nt = 0; nt < 5; nt++) sc[nt] = (f32x4){0.f, 0.f, 0.f, 0.f};
#pragma unroll
  for (int nt = 0; nt < 5; nt++) {
    int t = tb0 + nt * 16 + lr;
    int tc = t > 0 ? t : 0;
#pragma unroll
    for (int ks = 0; ks < 4; ks++) {
      bf16x8 bk = *(const bf16x8*)&k[kbase + (size_t)tc * INNER_DIM + ks * 32];
      sc[nt] = __builtin_amdgcn_mfma_f32_16x16x32_bf16(aq[ks], bk, sc[nt],
                                                       0, 0, 0);
    }
  }

  // ---- weights -> Ps cols [0,80) ----
#pragma unroll
  for (int nt = 0; nt < 5; nt++) {
    int t = tb0 + nt * 16 + lr;
    int tc = t > 0 ? t : 0;
    float bt = beta[((size_t)b * S_LEN + tc) * 8 + h];
#pragma unroll
    for (int reg = 0; reg < 4; reg++) {
      int qrow = sg + kq * 4 + reg;
      int td = qrow - t;
      float wgt = 0.0f;
      if (t >= 0 && td >= 0 && td < 64)
        wgt = sc[nt][reg] * __expf((float)td * la) * bt;
      Ps[w][kq * 4 + reg][nt * 16 + lr] = (bf16)wgt;
    }
  }
  // zero-fill cols [80,96): 16 rows x 16 cols spread over 64 lanes
#pragma unroll
  for (int j = 0; j < 4; j++)
    Ps[w][lr][80 + kq * 4 + j] = (bf16)0.0f;

  asm volatile("s_waitcnt lgkmcnt(0)" ::: "memory");
  __builtin_amdgcn_sched_barrier(0);

  // ---- PV: P(16x96) x V(96x128) over 3 ks2 windows ----
  bf16x8 ap[3];
#pragma unroll
  for (int ks2 = 0; ks2 < 3; ks2++)
    ap[ks2] = *(const bf16x8*)&Ps[w][lr][ks2 * 32 + kq * 8];

  f32x4 O[8];
#pragma unroll
  for (int en = 0; en < 8; en++) O[en] = (f32x4){0.f, 0.f, 0.f, 0.f};
#pragma unroll
  for (int en = 0; en < 8; en++) {
#pragma unroll
    for (int ks2 = 0; ks2 < 3; ks2++) {
      int t0f = tb0 + ks2 * 32 + kq * 8;
      int tcf = t0f < 0 ? 0 : (t0f > 2040 ? 2040 : t0f);
      bf16x8 bv = *(const bf16x8*)&vt[vtbase + (size_t)(en * 16 + lr) * 2048 +
                                      tcf];
      O[en] = __builtin_amdgcn_mfma_f32_16x16x32_bf16(ap[ks2], bv, O[en], 0,
                                                      0, 0);
    }
  }

  const size_t obase = (size_t)b * S_LEN * INNER_DIM + h * 128;
#pragma unroll
  for (int en = 0; en < 8; en++) {
#pragma unroll
    for (int reg = 0; reg < 4; reg++) {
      int qrow = sg + kq * 4 + reg;
      outb[obase + (size_t)qrow * INNER_DIM + en * 16 + lr] =
          (bf16)O[en][reg];
    }
  }
}

// ---------------------------------------------------------------------------
// Stage 1: partial state per 32-step chunk (unchanged).
// ---------------------------------------------------------------------------
__global__ __launch_bounds__(256) void state_partial_kernel(
    const bf16* __restrict__ k, const bf16* __restrict__ v,
    const float* __restrict__ beta, const float* __restrict__ la_d,
    float* __restrict__ part) {
  const int bh = blockIdx.x;
  const int chunk = blockIdx.y;
  const int b = bh >> 3, h = bh & 7;
  const int t0 = S_LEN - 512 + chunk * 32;
  const int tid = threadIdx.x;
  const int d = tid >> 1;
  const int eh = (tid & 1) * 64;

  __shared__ float ks[32][128];
  __shared__ float vsm[32][128];
  __shared__ float bs[32];

  const size_t bh_off = ((size_t)b * S_LEN) * INNER_DIM + (size_t)h * 128;
  for (int u = tid; u < 32 * 16; u += 256) {
    int r = u >> 4, c8 = (u & 15) * 8;
    bf16x8 kv = *(const bf16x8*)&k[bh_off + (size_t)(t0 + r) * INNER_DIM + c8];
    bf16x8 vv = *(const bf16x8*)&v[bh_off + (size_t)(t0 + r) * INNER_DIM + c8];
#pragma unroll
    for (int j = 0; j < 8; j++) {
      ks[r][c8 + j] = (float)kv[j];
      vsm[r][c8 + j] = (float)vv[j];
    }
  }
  if (tid < 32) bs[tid] = beta[((size_t)b * S_LEN + t0 + tid) * 8 + h];
  __syncthreads();

  const float lad = la_d[h * 128 + d];
  float acc[64];
#pragma unroll
  for (int e = 0; e < 64; e++) acc[e] = 0.0f;

  for (int tl = 0; tl < 32; tl++) {
    int m = (S_LEN - 1) - (t0 + tl);
    float f = __expf((float)m * lad);
    float coef = bs[tl] * ks[tl][d] * f;
    if (coef != 0.0f) {
#pragma unroll
      for (int e = 0; e < 64; e += 4) {
        float4 vv = *(const float4*)&vsm[tl][eh + e];
        acc[e + 0] = fmaf(coef, vv.x, acc[e + 0]);
        acc[e + 1] = fmaf(coef, vv.y, acc[e + 1]);
        acc[e + 2] = fmaf(coef, vv.z, acc[e + 2]);
        acc[e + 3] = fmaf(coef, vv.w, acc[e + 3]);
      }
    }
  }
  float* pp = part + (((size_t)chunk * 16 + bh) * 16384 + (size_t)d * 128 + eh);
#pragma unroll
  for (int e = 0; e < 64; e += 4) {
    float4 o = {acc[e + 0], acc[e + 1], acc[e + 2], acc[e + 3]};
    *(float4*)&pp[e] = o;
  }
}

// ---------------------------------------------------------------------------
extern "C" void kernel_launch(void* const* d_in, const int* in_sizes, int n_in,
                              void* d_out, int out_size, void* d_ws,
                              size_t ws_size, hipStream_t stream) {
  const float* x = (const float*)d_in[0];
  const float* Wq = (const float*)d_in[1];
  const float* Wk = (const float*)d_in[2];
  const float* Wv = (const float*)d_in[3];
  const float* Wo = (const float*)d_in[4];
  const float* Wb = (const float*)d_in[5];
  const float* bb = (const float*)d_in[6];
  const float* alog = (const float*)d_in[7];
  float* out = (float*)d_out;

  char* ws = (char*)d_ws;
  bf16* xb = (bf16*)(ws);                      // 16 MB
  float* part = (float*)(ws);                  // reuses xb after QKV GEMM
  bf16* wqkvb = (bf16*)(ws + 16777216UL);      // 12 MB
  bf16* wob = (bf16*)(ws + 29360128UL);        // 4 MB
  bf16* q = (bf16*)(ws + 33554432UL);          // 8 MB
  bf16* kk = (bf16*)(ws + 41943040UL);         // 8 MB
  bf16* vv = (bf16*)(ws + 50331648UL);         // 8 MB
  bf16* attnb = (bf16*)(ws + 58720256UL);      // 8 MB
  bf16* vt = (bf16*)(ws + 67108864UL);         // 8 MB (V transposed)
  float* beta = (float*)(ws + 75497472UL);     // 128 KB
  float* la_mean = (float*)(ws + 75628544UL);  // 32 B
  float* la_d = (float*)(ws + 75628800UL);     // 4 KB
  float2* cs = (float2*)(ws + 75632896UL);     // 1 MB rope table

  prep_kernel<<<9736, 256, 0, stream>>>(x, Wq, Wk, Wv, Wo, Wb, bb, alog,
                                        wqkvb, wob, xb, beta, la_mean, la_d,
                                        cs);
  // QKV GEMM with fused RoPE epilogue -> roped q/kk, vv (+ vt)
  qkv_gemm8p_kernel<<<256, 512, 0, stream>>>(xb, wqkvb, q, vt, cs);
  attn_mfma_kernel<<<dim3(S_LEN / 64, NHEADS, BATCH), 256, 0, stream>>>(
      q, kk, vt, beta, la_mean, attnb);
  state_partial_kernel<<<dim3(16, 16), 256, 0, stream>>>(kk, vv, beta, la_d,
                                                         part);
  // output projection (256 blocks) + state reduce (128 blocks), fused
  oproj_kernel<<<384, 512, 0, stream>>>(attnb, wob, out, part);
}

// Round 11
// 242.877 us; speedup vs baseline: 1.1280x; 1.0594x over previous
//
#include <hip/hip_runtime.h>
#include <hip/hip_bf16.h>
#include <cstdint>
#include <cstddef>

// Problem constants
#define S_LEN 2048
#define DMODEL 2048
#define NHEADS 8
#define DHEAD 128
#define INNER_DIM 1024
#define BATCH 2

typedef __bf16 bf16;
typedef __bf16 bf16x8 __attribute__((ext_vector_type(8)));
typedef __bf16 bf16x4 __attribute__((ext_vector_type(4)));
typedef float f32x4 __attribute__((ext_vector_type(4)));

#define VMCNT(n) asm volatile("s_waitcnt vmcnt(" #n ")" ::: "memory")
#define BAR()                                \
  do {                                       \
    asm volatile("" ::: "memory");           \
    __builtin_amdgcn_s_barrier();            \
    asm volatile("" ::: "memory");           \
  } while (0)

__device__ __forceinline__ void gload_lds16(const void* g, void* l) {
  __builtin_amdgcn_global_load_lds(
      (const __attribute__((address_space(1))) void*)g,
      (__attribute__((address_space(3))) void*)l, 16, 0, 0);
}

__device__ __forceinline__ float sigmoidf_(float x) {
  return 1.0f / (1.0f + expf(-x));
}

// ---------------------------------------------------------------------------
// Fused prep kernel, range-dispatched on blockIdx.x (unchanged).
// ---------------------------------------------------------------------------
__global__ __launch_bounds__(256) void prep_kernel(
    const float* __restrict__ x, const float* __restrict__ wq,
    const float* __restrict__ wk, const float* __restrict__ wv,
    const float* __restrict__ wo, const float* __restrict__ Wb,
    const float* __restrict__ bbias, const float* __restrict__ alpha_log,
    bf16* __restrict__ wqkvb, bf16* __restrict__ wob, bf16* __restrict__ xb,
    float* __restrict__ beta, float* __restrict__ la_mean,
    float* __restrict__ la_d, float2* __restrict__ cs) {
  const int bid = blockIdx.x;
  const int tid = threadIdx.x;

  if (bid < 8192) {
    size_t i4 = ((size_t)bid * 256 + tid) * 4;
    const float* src;
    bf16* dst;
    size_t off;
    if (i4 < 2097152UL)       { src = wq; dst = wqkvb;           off = i4; }
    else if (i4 < 4194304UL)  { src = wk; dst = wqkvb + 2097152; off = i4 - 2097152UL; }
    else if (i4 < 6291456UL)  { src = wv; dst = wqkvb + 4194304; off = i4 - 4194304UL; }
    else                      { src = wo; dst = wob;             off = i4 - 6291456UL; }
    float4 v = *(const float4*)(src + off);
    bf16x4 o;
    o[0] = (bf16)v.x; o[1] = (bf16)v.y; o[2] = (bf16)v.z; o[3] = (bf16)v.w;
    *(bf16x4*)(dst + off) = o;
  } else if (bid < 9216) {
    const int n = (bid - 8192) * 4 + (tid >> 6);
    const int lane = tid & 63;
    float acc[8];
#pragma unroll
    for (int h = 0; h < 8; h++) acc[h] = 0.0f;
    const float4* x4 = (const float4*)(x + (size_t)n * DMODEL);
    bf16* xbr = xb + (size_t)n * DMODEL;
    for (int d4 = lane; d4 < DMODEL / 4; d4 += 64) {
      float4 xv = x4[d4];
      bf16x4 o;
      o[0] = (bf16)xv.x; o[1] = (bf16)xv.y; o[2] = (bf16)xv.z; o[3] = (bf16)xv.w;
      *(bf16x4*)(xbr + d4 * 4) = o;
#pragma unroll
      for (int h = 0; h < 8; h++) {
        float4 wv2 = ((const float4*)(Wb + (size_t)h * DMODEL))[d4];
        acc[h] += xv.x * wv2.x + xv.y * wv2.y + xv.z * wv2.z + xv.w * wv2.w;
      }
    }
#pragma unroll
    for (int off = 32; off; off >>= 1)
#pragma unroll
      for (int h = 0; h < 8; h++) acc[h] += __shfl_down(acc[h], off);
    if (lane == 0) {
#pragma unroll
      for (int h = 0; h < 8; h++)
        beta[(size_t)n * 8 + h] = sigmoidf_(acc[h] + bbias[h]);
    }
  } else if (bid < 9728) {
    int idx = (bid - 9216) * 256 + tid;  // < 131072 = 2048*64
    int s = idx >> 6, j = idx & 63;
    float f = (float)s * expf(-(float)j * (9.210340371976184f / 64.0f));
    float sn, c;
    sincosf(f, &sn, &c);
    cs[idx] = make_float2(c, sn);
  } else {
    if (tid >= 64) return;
    const int h = bid - 9728;
    const int lane = tid;
    float a1 = sigmoidf_(alpha_log[h * 128 + lane]);
    float a2 = sigmoidf_(alpha_log[h * 128 + 64 + lane]);
    la_d[h * 128 + lane] = logf(a1);
    la_d[h * 128 + 64 + lane] = logf(a2);
    float s = a1 + a2;
    for (int off = 32; off; off >>= 1) s += __shfl_down(s, off);
    if (lane == 0) la_mean[h] = logf(fmaxf(s * (1.0f / 128.0f), 1e-6f));
  }
}

// ---------------------------------------------------------------------------
// QKV projection with fused RoPE epilogue (round-9 verified, ~61 us).
// ---------------------------------------------------------------------------
#define QKV_K 2048
#define QKV_NT 32  // K / 64
#define LSTR 392   // epilogue LDS stride (elems)

__global__ __launch_bounds__(512, 2) void qkv_gemm8p_kernel(
    const bf16* __restrict__ A, const bf16* __restrict__ Bm,
    bf16* __restrict__ C, bf16* __restrict__ vt,
    const float2* __restrict__ cs) {
  __shared__ __align__(16) bf16 smem[2][32768];  // buf: A[0,8192) B[8192,32768)

  const int id = blockIdx.x;
  const int wg = (id & 7) * 32 + (id >> 3);
  const int tile_n = (wg >> 5) * 384;
  const int tile_m = (wg & 31) * 128;

  const int tid = threadIdx.x;
  const int lane = tid & 63;
  const int w = tid >> 6;
  const int wm = w >> 2;  // 0..1 -> rows wm*64
  const int wn = w & 3;   // 0..3 -> cols wn*96
  const int lr = lane & 15;
  const int kq = lane >> 4;

  const int srow = lane >> 3;
  const int slot = lane & 7;
  const int sgo = (slot ^ srow) * 8;
  const int rloc = w * 8 + srow;

  size_t Aoff[2], Boff[6];
#pragma unroll
  for (int a = 0; a < 2; ++a)
    Aoff[a] = (size_t)(tile_m + a * 64 + rloc) * QKV_K + sgo;
#pragma unroll
  for (int b = 0; b < 6; ++b) {
    const int ldsr = b * 64 + rloc;
    const int qn = ldsr >= 192 ? 1 : 0;
    const int rem = ldsr - qn * 192;
    const int wng = rem / 48;
    const int rr = rem - wng * 48;
    const int gcol = wng * 96 + qn * 48 + rr;
    Boff[b] = (size_t)(tile_n + gcol) * QKV_K + sgo;
  }

  f32x4 acc[4][6];
#pragma unroll
  for (int i = 0; i < 4; i++)
#pragma unroll
    for (int j = 0; j < 6; j++) acc[i][j] = (f32x4){0.f, 0.f, 0.f, 0.f};

  auto stageAA = [&](int buf, int k0) {
#pragma unroll
    for (int a = 0; a < 2; ++a)
      gload_lds16(A + Aoff[a] + k0, &smem[buf][(a * 64 + w * 8) * 64]);
  };
  auto stageB2 = [&](int buf, int k0, int b0) {
#pragma unroll
    for (int u = 0; u < 2; ++u)
      gload_lds16(Bm + Boff[b0 + u] + k0,
                  &smem[buf][8192 + ((b0 + u) * 64 + w * 8) * 64]);
  };

  // prologue (order matters for the ledger)
  stageAA(0, 0);
  stageB2(0, 0, 0);
  stageB2(0, 0, 2);
  stageAA(1, 64);
  stageB2(0, 0, 4);
  VMCNT(4);
  BAR();

  for (int t = 0; t < QKV_NT; ++t) {
    const int buf = t & 1;
    const int k0n = (t + 1) * 64;
    const bool h1 = (t + 1 < QKV_NT);
    const bool h2 = (t + 2 < QKV_NT);
    const bf16* ldsA = smem[buf];
    const bf16* ldsB = smem[buf] + 8192;

    bf16x8 af[2][2], b0f[3][2], b1f[3][2];

    // ---- p0: read A-q0 + B-q0; stage b01(t+1); MFMA (0,0..2) ----
#pragma unroll
    for (int mi = 0; mi < 2; ++mi)
#pragma unroll
      for (int ks = 0; ks < 2; ++ks)
        af[mi][ks] = *(const bf16x8*)&ldsA[(wm * 64 + mi * 16 + lr) * 64 +
                                           (((ks * 4 + kq) ^ (lr & 7)) * 8)];
#pragma unroll
    for (int ni = 0; ni < 3; ++ni)
#pragma unroll
      for (int ks = 0; ks < 2; ++ks)
        b0f[ni][ks] = *(const bf16x8*)&ldsB[(wn * 48 + ni * 16 + lr) * 64 +
                                            (((ks * 4 + kq) ^ (lr & 7)) * 8)];
    if (h1) stageB2(buf ^ 1, k0n, 0);
    __builtin_amdgcn_s_setprio(1);
#pragma unroll
    for (int mi = 0; mi < 2; ++mi)
#pragma unroll
      for (int ni = 0; ni < 3; ++ni)
#pragma unroll
        for (int ks = 0; ks < 2; ++ks)
          acc[mi][ni] = __builtin_amdgcn_mfma_f32_16x16x32_bf16(
              af[mi][ks], b0f[ni][ks], acc[mi][ni], 0, 0, 0);
    __builtin_amdgcn_s_setprio(0);
    if (h1) VMCNT(4);
    else VMCNT(0);
    BAR();

    // ---- p1: read B-q1; stage b23(t+1); MFMA (0,3..5) ----
#pragma unroll
    for (int ni = 0; ni < 3; ++ni)
#pragma unroll
      for (int ks = 0; ks < 2; ++ks)
        b1f[ni][ks] = *(const bf16x8*)&ldsB[(192 + wn * 48 + ni * 16 + lr) * 64 +
                                            (((ks * 4 + kq) ^ (lr & 7)) * 8)];
    if (h1) stageB2(buf ^ 1, k0n, 2);
    __builtin_amdgcn_s_setprio(1);
#pragma unroll
    for (int mi = 0; mi < 2; ++mi)
#pragma unroll
      for (int ni = 0; ni < 3; ++ni)
#pragma unroll
        for (int ks = 0; ks < 2; ++ks)
          acc[mi][3 + ni] = __builtin_amdgcn_mfma_f32_16x16x32_bf16(
              af[mi][ks], b1f[ni][ks], acc[mi][3 + ni], 0, 0, 0);
    __builtin_amdgcn_s_setprio(0);
    BAR();

    // ---- p2: read A-q1 (overwrite); stage b45(t+1); MFMA (1,3..5) ----
#pragma unroll
    for (int mi = 0; mi < 2; ++mi)
#pragma unroll
      for (int ks = 0; ks < 2; ++ks)
        af[mi][ks] = *(const bf16x8*)&ldsA[(wm * 64 + 32 + mi * 16 + lr) * 64 +
                                           (((ks * 4 + kq) ^ (lr & 7)) * 8)];
    if (h1) stageB2(buf ^ 1, k0n, 4);
    __builtin_amdgcn_s_setprio(1);
#pragma unroll
    for (int mi = 0; mi < 2; ++mi)
#pragma unroll
      for (int ni = 0; ni < 3; ++ni)
#pragma unroll
        for (int ks = 0; ks < 2; ++ks)
          acc[2 + mi][3 + ni] = __builtin_amdgcn_mfma_f32_16x16x32_bf16(
              af[mi][ks], b1f[ni][ks], acc[2 + mi][3 + ni], 0, 0, 0);
    __builtin_amdgcn_s_setprio(0);
    BAR();

    // ---- p3: stage A(t+2) into CURRENT buf; MFMA (1,0..2) ----
    if (h2) stageAA(buf, (t + 2) * 64);
    __builtin_amdgcn_s_setprio(1);
#pragma unroll
    for (int mi = 0; mi < 2; ++mi)
#pragma unroll
      for (int ni = 0; ni < 3; ++ni)
#pragma unroll
        for (int ks = 0; ks < 2; ++ks)
          acc[2 + mi][ni] = __builtin_amdgcn_mfma_f32_16x16x32_bf16(
              af[mi][ks], b0f[ni][ks], acc[2 + mi][ni], 0, 0, 0);
    __builtin_amdgcn_s_setprio(0);
    if (h1) {
      if (h2) VMCNT(4);
      else VMCNT(2);
    }
    BAR();
  }

  // -------- epilogue: fused rope for z<2; v/vt unchanged --------
  bf16* Ls = &smem[0][0];  // reuse dead staging LDS, stride LSTR
  const int rb = kq * 4;
  const bool anyrope = tile_n < 2048;

  if (anyrope) {
#pragma unroll
    for (int mi = 0; mi < 4; ++mi) {
      const int rowL = wm * 64 + mi * 16 + rb;
#pragma unroll
      for (int ni = 0; ni < 6; ++ni) {
        const int colL = wn * 96 + ni * 16 + lr;
        if (tile_n + colL < 2048) {
#pragma unroll
          for (int r2 = 0; r2 < 4; ++r2)
            Ls[(rowL + r2) * LSTR + colL] = (bf16)acc[mi][ni][r2];
        }
      }
    }
    BAR();
  }

#pragma unroll
  for (int mi = 0; mi < 4; ++mi) {
    const int row0 = tile_m + wm * 64 + mi * 16 + rb;
    const int rowL0 = wm * 64 + mi * 16 + rb;
#pragma unroll
    for (int ni = 0; ni < 6; ++ni) {
      const int colL = wn * 96 + ni * 16 + lr;
      const int col = tile_n + colL;
      const int z = col >> 10;
      const int cz = col & 1023;
      bf16* Cz = C + (size_t)z * 4194304UL;
      if (z < 2) {
        const int d = col & 127;
        const int dj = d & 63;
        const bool lohalf = d < 64;
        const int colP = colL + (lohalf ? 64 : -64);
#pragma unroll
        for (int r2 = 0; r2 < 4; ++r2) {
          float own = acc[mi][ni][r2];
          float par = (float)Ls[(rowL0 + r2) * LSTR + colP];
          float2 cv = cs[(size_t)((row0 + r2) & 2047) * 64 + dj];
          float o = lohalf ? (own * cv.x - par * cv.y)
                           : (own * cv.x + par * cv.y);
          Cz[(size_t)(row0 + r2) * 1024 + cz] = (bf16)o;
        }
      } else {
#pragma unroll
        for (int r2 = 0; r2 < 4; ++r2)
          Cz[(size_t)(row0 + r2) * 1024 + cz] = (bf16)acc[mi][ni][r2];
        const int bb2 = row0 >> 11;
        const int ss = row0 & 2047;
        bf16x4 o4;
#pragma unroll
        for (int r2 = 0; r2 < 4; ++r2) o4[r2] = (bf16)acc[mi][ni][r2];
        *(bf16x4*)&vt[(((size_t)bb2 * 8 + (cz >> 7)) * 128 + (cz & 127)) * 2048 +
                      ss] = o4;
      }
    }
  }
}

// ---------------------------------------------------------------------------
// Output projection (bid<256) + state reduce (bid>=256), fused launch.
// ---------------------------------------------------------------------------
#define OP_K 1024
#define OP_NT 16  // K / 64

__global__ __launch_bounds__(512, 2) void oproj_kernel(
    const bf16* __restrict__ A, const bf16* __restrict__ Bm,
    float* __restrict__ C, const float* __restrict__ part) {
  __shared__ __align__(16) bf16 smem[2][24576];  // A[0,8192) B[8192,24576)

  const int id = blockIdx.x;
  const int tid = threadIdx.x;

  if (id >= 256) {
    // ---- state reduce: sum 16 chunk partials ----
    size_t off = (((size_t)id - 256) * 512 + tid) * 4;
    float4 s = {0.f, 0.f, 0.f, 0.f};
#pragma unroll
    for (int c = 0; c < 16; c++) {
      float4 p = *(const float4*)&part[(size_t)c * 262144 + off];
      s.x += p.x; s.y += p.y; s.z += p.z; s.w += p.w;
    }
    *(float4*)&C[8388608UL + off] = s;
    return;
  }

  const int wg = (id & 7) * 32 + (id >> 3);
  const int tile_n = (wg >> 5) * 256;
  const int tile_m = (wg & 31) * 128;

  const int lane = tid & 63;
  const int w = tid >> 6;
  const int wm = w >> 2;  // 0..1
  const int wn = w & 3;   // 0..3
  const int lr = lane & 15;
  const int kq = lane >> 4;

  const int srow = lane >> 3;
  const int slot = lane & 7;
  const int sgo = (slot ^ srow) * 8;
  const int rloc = w * 8 + srow;

  size_t Aoff[2], Boff[4];
#pragma unroll
  for (int a = 0; a < 2; ++a)
    Aoff[a] = (size_t)(tile_m + a * 64 + rloc) * OP_K + sgo;
#pragma unroll
  for (int b = 0; b < 4; ++b) {
    const int ldsr = b * 64 + rloc;
    const int qn = ldsr >= 128 ? 1 : 0;
    const int rem = ldsr - qn * 128;
    const int wng = rem >> 5;
    const int rr = rem & 31;
    const int gcol = wng * 64 + qn * 32 + rr;
    Boff[b] = (size_t)(tile_n + gcol) * OP_K + sgo;
  }

  f32x4 acc[4][4];
#pragma unroll
  for (int i = 0; i < 4; i++)
#pragma unroll
    for (int j = 0; j < 4; j++) acc[i][j] = (f32x4){0.f, 0.f, 0.f, 0.f};

  auto stageAA = [&](int buf, int k0) {
#pragma unroll
    for (int a = 0; a < 2; ++a)
      gload_lds16(A + Aoff[a] + k0, &smem[buf][(a * 64 + w * 8) * 64]);
  };
  auto stageB2 = [&](int buf, int k0, int b0) {
#pragma unroll
    for (int u = 0; u < 2; ++u)
      gload_lds16(Bm + Boff[b0 + u] + k0,
                  &smem[buf][8192 + ((b0 + u) * 64 + w * 8) * 64]);
  };

  // prologue
  stageAA(0, 0);
  stageB2(0, 0, 0);
  stageAA(1, 64);
  stageB2(0, 0, 2);
  VMCNT(4);
  BAR();

  for (int t = 0; t < OP_NT; ++t) {
    const int buf = t & 1;
    const int k0n = (t + 1) * 64;
    const bool h1 = (t + 1 < OP_NT);
    const bool h2 = (t + 2 < OP_NT);
    const bf16* ldsA = smem[buf];
    const bf16* ldsB = smem[buf] + 8192;

    bf16x8 af[2][2], b0f[2][2], b1f[2][2];

    // ---- p0 ----
#pragma unroll
    for (int mi = 0; mi < 2; ++mi)
#pragma unroll
      for (int ks = 0; ks < 2; ++ks)
        af[mi][ks] = *(const bf16x8*)&ldsA[(wm * 64 + mi * 16 + lr) * 64 +
                                           (((ks * 4 + kq) ^ (lr & 7)) * 8)];
#pragma unroll
    for (int ni = 0; ni < 2; ++ni)
#pragma unroll
      for (int ks = 0; ks < 2; ++ks)
        b0f[ni][ks] = *(const bf16x8*)&ldsB[(wn * 32 + ni * 16 + lr) * 64 +
                                            (((ks * 4 + kq) ^ (lr & 7)) * 8)];
    if (h1) stageB2(buf ^ 1, k0n, 0);
    __builtin_amdgcn_s_setprio(1);
#pragma unroll
    for (int mi = 0; mi < 2; ++mi)
#pragma unroll
      for (int ni = 0; ni < 2; ++ni)
#pragma unroll
        for (int ks = 0; ks < 2; ++ks)
          acc[mi][ni] = __builtin_amdgcn_mfma_f32_16x16x32_bf16(
              af[mi][ks], b0f[ni][ks], acc[mi][ni], 0, 0, 0);
    __builtin_amdgcn_s_setprio(0);
    if (h1) VMCNT(4);
    else VMCNT(0);
    BAR();

    // ---- p1 ----
#pragma unroll
    for (int ni = 0; ni < 2; ++ni)
#pragma unroll
      for (int ks = 0; ks < 2; ++ks)
        b1f[ni][ks] = *(const bf16x8*)&ldsB[(128 + wn * 32 + ni * 16 + lr) * 64 +
                                            (((ks * 4 + kq) ^ (lr & 7)) * 8)];
    if (h1) stageB2(buf ^ 1, k0n, 2);
    __builtin_amdgcn_s_setprio(1);
#pragma unroll
    for (int mi = 0; mi < 2; ++mi)
#pragma unroll
      for (int ni = 0; ni < 2; ++ni)
#pragma unroll
        for (int ks = 0; ks < 2; ++ks)
          acc[mi][2 + ni] = __builtin_amdgcn_mfma_f32_16x16x32_bf16(
              af[mi][ks], b1f[ni][ks], acc[mi][2 + ni], 0, 0, 0);
    __builtin_amdgcn_s_setprio(0);
    BAR();

    // ---- p2 ----
#pragma unroll
    for (int mi = 0; mi < 2; ++mi)
#pragma unroll
      for (int ks = 0; ks < 2; ++ks)
        af[mi][ks] = *(const bf16x8*)&ldsA[(wm * 64 + 32 + mi * 16 + lr) * 64 +
                                           (((ks * 4 + kq) ^ (lr & 7)) * 8)];
    __builtin_amdgcn_s_setprio(1);
#pragma unroll
    for (int mi = 0; mi < 2; ++mi)
#pragma unroll
      for (int ni = 0; ni < 2; ++ni)
#pragma unroll
        for (int ks = 0; ks < 2; ++ks)
          acc[2 + mi][2 + ni] = __builtin_amdgcn_mfma_f32_16x16x32_bf16(
              af[mi][ks], b1f[ni][ks], acc[2 + mi][2 + ni], 0, 0, 0);
    __builtin_amdgcn_s_setprio(0);
    BAR();

    // ---- p3 ----
    if (h2) stageAA(buf, (t + 2) * 64);
    __builtin_amdgcn_s_setprio(1);
#pragma unroll
    for (int mi = 0; mi < 2; ++mi)
#pragma unroll
      for (int ni = 0; ni < 2; ++ni)
#pragma unroll
        for (int ks = 0; ks < 2; ++ks)
          acc[2 + mi][ni] = __builtin_amdgcn_mfma_f32_16x16x32_bf16(
              af[mi][ks], b0f[ni][ks], acc[2 + mi][ni], 0, 0, 0);
    __builtin_amdgcn_s_setprio(0);
    if (h1) {
      if (h2) VMCNT(4);
      else VMCNT(2);
    }
    BAR();
  }

  // epilogue: fp32 C
  const int rb = kq * 4;
#pragma unroll
  for (int i = 0; i < 4; ++i) {
    const int row0 = tile_m + wm * 64 + (i >> 1) * 32 + (i & 1) * 16 + rb;
#pragma unroll
    for (int j = 0; j < 4; ++j) {
      const int col = tile_n + wn * 64 + (j >> 1) * 32 + (j & 1) * 16 + lr;
#pragma unroll
      for (int r2 = 0; r2 < 4; ++r2)
        C[(size_t)(row0 + r2) * 2048 + col] = acc[i][j][r2];
    }
  }
}

// ---------------------------------------------------------------------------
// ROUND-11: attn (bid<512, window-aligned round-10 schedule) + state_partial
// (bid>=512) fused into one launch. Branches are block-uniform; shared
// memory unioned via one 33KB byte array (attn: 13.3KB Ps; state: 32.9KB).
// Per-branch code byte-identical to round 10.
// ---------------------------------------------------------------------------
__global__ __launch_bounds__(256) void attn_state_kernel(
    const bf16* __restrict__ q, const bf16* __restrict__ k,
    const bf16* __restrict__ vt, const bf16* __restrict__ v,
    const float* __restrict__ beta, const float* __restrict__ la_mean,
    const float* __restrict__ la_d, bf16* __restrict__ outb,
    float* __restrict__ part) {
  __shared__ __align__(16) char smraw[33024];
  const int bid = blockIdx.x;
  const int tid = threadIdx.x;

  if (bid < 512) {
    // ================= attn branch =================
    const int s0 = (bid & 31) * 64;
    const int h = (bid >> 5) & 7;
    const int b = bid >> 8;
    const int w = tid >> 6;
    const int lane = tid & 63;
    const int lr = lane & 15;
    const int kq = lane >> 4;  // quad
    const float la = la_mean[h];

    bf16 (*Ps)[16][104] = (bf16(*)[16][104])smraw;

    const int sg = s0 + w * 16;   // wave's first q row
    const int tb0 = sg - 64;      // wave's window start

    const size_t qbase =
        ((size_t)b * S_LEN + (sg + lr)) * INNER_DIM + h * 128 + kq * 8;
    bf16x8 aq[4];
#pragma unroll
    for (int ks = 0; ks < 4; ks++)
      aq[ks] = *(const bf16x8*)&q[qbase + ks * 32];

    const size_t kbase = (size_t)b * S_LEN * INNER_DIM + h * 128 + kq * 8;
    const size_t vtbase = ((size_t)b * 8 + h) * 128 * 2048;

    // ---- QK^T: 5 nt tiles covering t in [sg-64, sg+16) ----
    f32x4 sc[5];
#pragma unroll
    for (int nt = 0; nt < 5; nt++) sc[nt] = (f32x4){0.f, 0.f, 0.f, 0.f};
#pragma unroll
    for (int nt = 0; nt < 5; nt++) {
      int t = tb0 + nt * 16 + lr;
      int tc = t > 0 ? t : 0;
#pragma unroll
      for (int ks = 0; ks < 4; ks++) {
        bf16x8 bk = *(const bf16x8*)&k[kbase + (size_t)tc * INNER_DIM + ks * 32];
        sc[nt] = __builtin_amdgcn_mfma_f32_16x16x32_bf16(aq[ks], bk, sc[nt],
                                                         0, 0, 0);
      }
    }

    // ---- weights -> Ps cols [0,80) ----
#pragma unroll
    for (int nt = 0; nt < 5; nt++) {
      int t = tb0 + nt * 16 + lr;
      int tc = t > 0 ? t : 0;
      float bt = beta[((size_t)b * S_LEN + tc) * 8 + h];
#pragma unroll
      for (int reg = 0; reg < 4; reg++) {
        int qrow = sg + kq * 4 + reg;
        int td = qrow - t;
        float wgt = 0.0f;
        if (t >= 0 && td >= 0 && td < 64)
          wgt = sc[nt][reg] * __expf((float)td * la) * bt;
        Ps[w][kq * 4 + reg][nt * 16 + lr] = (bf16)wgt;
      }
    }
    // zero-fill cols [80,96)
#pragma unroll
    for (int j = 0; j < 4; j++)
      Ps[w][lr][80 + kq * 4 + j] = (bf16)0.0f;

    asm volatile("s_waitcnt lgkmcnt(0)" ::: "memory");
    __builtin_amdgcn_sched_barrier(0);

    // ---- PV: P(16x96) x V(96x128) over 3 ks2 windows ----
    bf16x8 ap[3];
#pragma unroll
    for (int ks2 = 0; ks2 < 3; ks2++)
      ap[ks2] = *(const bf16x8*)&Ps[w][lr][ks2 * 32 + kq * 8];

    f32x4 O[8];
#pragma unroll
    for (int en = 0; en < 8; en++) O[en] = (f32x4){0.f, 0.f, 0.f, 0.f};
#pragma unroll
    for (int en = 0; en < 8; en++) {
#pragma unroll
      for (int ks2 = 0; ks2 < 3; ks2++) {
        int t0f = tb0 + ks2 * 32 + kq * 8;
        int tcf = t0f < 0 ? 0 : (t0f > 2040 ? 2040 : t0f);
        bf16x8 bv = *(const bf16x8*)&vt[vtbase + (size_t)(en * 16 + lr) * 2048 +
                                        tcf];
        O[en] = __builtin_amdgcn_mfma_f32_16x16x32_bf16(ap[ks2], bv, O[en], 0,
                                                        0, 0);
      }
    }

    const size_t obase = (size_t)b * S_LEN * INNER_DIM + h * 128;
#pragma unroll
    for (int en = 0; en < 8; en++) {
#pragma unroll
      for (int reg = 0; reg < 4; reg++) {
        int qrow = sg + kq * 4 + reg;
        outb[obase + (size_t)qrow * INNER_DIM + en * 16 + lr] =
            (bf16)O[en][reg];
      }
    }
  } else {
    // ================= state_partial branch =================
    const int idx = bid - 512;
    const int bh = idx & 15;
    const int chunk = idx >> 4;
    const int b = bh >> 3, h = bh & 7;
    const int t0 = S_LEN - 512 + chunk * 32;
    const int d = tid >> 1;
    const int eh = (tid & 1) * 64;

    float (*ks)[128] = (float(*)[128])smraw;
    float (*vsm)[128] = (float(*)[128])(smraw + 16384);
    float* bs = (float*)(smraw + 32768);

    const size_t bh_off = ((size_t)b * S_LEN) * INNER_DIM + (size_t)h * 128;
    for (int u = tid; u < 32 * 16; u += 256) {
      int r = u >> 4, c8 = (u & 15) * 8;
      bf16x8 kv = *(const bf16x8*)&k[bh_off + (size_t)(t0 + r) * INNER_DIM + c8];
      bf16x8 vv8 = *(const bf16x8*)&v[bh_off + (size_t)(t0 + r) * INNER_DIM + c8];
#pragma unroll
      for (int j = 0; j < 8; j++) {
        ks[r][c8 + j] = (float)kv[j];
        vsm[r][c8 + j] = (float)vv8[j];
      }
    }
    if (tid < 32) bs[tid] = beta[((size_t)b * S_LEN + t0 + tid) * 8 + h];
    __syncthreads();

    const float lad = la_d[h * 128 + d];
    float acc[64];
#pragma unroll
    for (int e = 0; e < 64; e++) acc[e] = 0.0f;

    for (int tl = 0; tl < 32; tl++) {
      int m = (S_LEN - 1) - (t0 + tl);
      float f = __expf((float)m * lad);
      float coef = bs[tl] * ks[tl][d] * f;
      if (coef != 0.0f) {
#pragma unroll
        for (int e = 0; e < 64; e += 4) {
          float4 vv4 = *(const float4*)&vsm[tl][eh + e];
          acc[e + 0] = fmaf(coef, vv4.x, acc[e + 0]);
          acc[e + 1] = fmaf(coef, vv4.y, acc[e + 1]);
          acc[e + 2] = fmaf(coef, vv4.z, acc[e + 2]);
          acc[e + 3] = fmaf(coef, vv4.w, acc[e + 3]);
        }
      }
    }
    float* pp =
        part + (((size_t)chunk * 16 + bh) * 16384 + (size_t)d * 128 + eh);
#pragma unroll
    for (int e = 0; e < 64; e += 4) {
      float4 o = {acc[e + 0], acc[e + 1], acc[e + 2], acc[e + 3]};
      *(float4*)&pp[e] = o;
    }
  }
}

// ---------------------------------------------------------------------------
extern "C" void kernel_launch(void* const* d_in, const int* in_sizes, int n_in,
                              void* d_out, int out_size, void* d_ws,
                              size_t ws_size, hipStream_t stream) {
  const float* x = (const float*)d_in[0];
  const float* Wq = (const float*)d_in[1];
  const float* Wk = (const float*)d_in[2];
  const float* Wv = (const float*)d_in[3];
  const float* Wo = (const float*)d_in[4];
  const float* Wb = (const float*)d_in[5];
  const float* bb = (const float*)d_in[6];
  const float* alog = (const float*)d_in[7];
  float* out = (float*)d_out;

  char* ws = (char*)d_ws;
  bf16* xb = (bf16*)(ws);                      // 16 MB
  float* part = (float*)(ws);                  // reuses xb after QKV GEMM
  bf16* wqkvb = (bf16*)(ws + 16777216UL);      // 12 MB
  bf16* wob = (bf16*)(ws + 29360128UL);        // 4 MB
  bf16* q = (bf16*)(ws + 33554432UL);          // 8 MB
  bf16* kk = (bf16*)(ws + 41943040UL);         // 8 MB
  bf16* vv = (bf16*)(ws + 50331648UL);         // 8 MB
  bf16* attnb = (bf16*)(ws + 58720256UL);      // 8 MB
  bf16* vt = (bf16*)(ws + 67108864UL);         // 8 MB (V transposed)
  float* beta = (float*)(ws + 75497472UL);     // 128 KB
  float* la_mean = (float*)(ws + 75628544UL);  // 32 B
  float* la_d = (float*)(ws + 75628800UL);     // 4 KB
  float2* cs = (float2*)(ws + 75632896UL);     // 1 MB rope table

  prep_kernel<<<9736, 256, 0, stream>>>(x, Wq, Wk, Wv, Wo, Wb, bb, alog,
                                        wqkvb, wob, xb, beta, la_mean, la_d,
                                        cs);
  // QKV GEMM with fused RoPE epilogue -> roped q/kk, vv (+ vt)
  qkv_gemm8p_kernel<<<256, 512, 0, stream>>>(xb, wqkvb, q, vt, cs);
  // attn (512 blocks) + state_partial (256 blocks), fused
  attn_state_kernel<<<768, 256, 0, stream>>>(q, kk, vt, vv, beta, la_mean,
                                             la_d, attnb, part);
  // output projection (256 blocks) + state reduce (128 blocks), fused
  oproj_kernel<<<384, 512, 0, stream>>>(attnb, wob, out, part);
}